// Round 1
// baseline (497.984 us; speedup 1.0000x reference)
//
#include <hip/hip_runtime.h>
#include <math.h>

using bf16   = __bf16;
using bf16x8 = __attribute__((ext_vector_type(8))) __bf16;
using bf16x4 = __attribute__((ext_vector_type(4))) __bf16;
using f32x4  = __attribute__((ext_vector_type(4))) float;

#define MFMA_16x16x32(a, b, c) __builtin_amdgcn_mfma_f32_16x16x32_bf16((a), (b), (c), 0, 0, 0)

__device__ __forceinline__ void gll16(const void* g, void* l) {
  __builtin_amdgcn_global_load_lds((const __attribute__((address_space(1))) void*)g,
                                   (__attribute__((address_space(3))) void*)l,
                                   16, 0, 0);
}

// ---------------- fp32 -> bf16 cast ----------------
__global__ __launch_bounds__(256) void cast_bf16_kernel(const float* __restrict__ in,
                                                        bf16* __restrict__ out, int n4) {
  int i = blockIdx.x * 256 + threadIdx.x;
  if (i < n4) {
    float4 v = ((const float4*)in)[i];
    bf16x4 o;
    o[0] = (bf16)v.x; o[1] = (bf16)v.y; o[2] = (bf16)v.z; o[3] = (bf16)v.w;
    ((bf16x4*)out)[i] = o;
  }
}

// ---------------- LayerNorm (D=1024), fp32 in -> bf16 out ----------------
__global__ __launch_bounds__(256) void ln_kernel(const float* __restrict__ x,
                                                 const float* __restrict__ g,
                                                 const float* __restrict__ b,
                                                 bf16* __restrict__ out) {
  const int row = blockIdx.x, t = threadIdx.x;
  const float4 v = ((const float4*)(x + (size_t)row * 1024))[t];
  float s1 = v.x + v.y + v.z + v.w;
  float s2 = v.x * v.x + v.y * v.y + v.z * v.z + v.w * v.w;
#pragma unroll
  for (int d = 32; d; d >>= 1) {
    s1 += __shfl_xor(s1, d);
    s2 += __shfl_xor(s2, d);
  }
  __shared__ float red[8];
  const int w = t >> 6;
  if ((t & 63) == 0) { red[w] = s1; red[4 + w] = s2; }
  __syncthreads();
  s1 = red[0] + red[1] + red[2] + red[3];
  s2 = red[4] + red[5] + red[6] + red[7];
  const float mu = s1 * (1.f / 1024.f);
  const float rstd = rsqrtf(s2 * (1.f / 1024.f) - mu * mu + 1e-5f);
  const float4 gv = ((const float4*)g)[t];
  const float4 bv = ((const float4*)b)[t];
  bf16x4 o;
  o[0] = (bf16)((v.x - mu) * rstd * gv.x + bv.x);
  o[1] = (bf16)((v.y - mu) * rstd * gv.y + bv.y);
  o[2] = (bf16)((v.z - mu) * rstd * gv.z + bv.z);
  o[3] = (bf16)((v.w - mu) * rstd * gv.w + bv.w);
  ((bf16x4*)(out + (size_t)row * 1024))[t] = o;
}

// ---------------- GEMM: C[M,N] = A[M,K] @ W[N,K]^T (+epilogue) ----------------
// EPI 0: +bias -> bf16 out | 1: +bias, gelu(erf) -> bf16 out | 2: +bias +resid -> f32 out
// M fixed 4096. 128x128 tile, BK=32, 256 threads (4 waves, 2x2), 4x4 16x16x32 frags/wave.
template <int EPI>
__global__ __launch_bounds__(256) void gemm_bt(const bf16* __restrict__ A,
                                               const bf16* __restrict__ W,
                                               const float* __restrict__ bias,
                                               const float* __restrict__ resid,
                                               void* __restrict__ outp, int N, int K) {
  __shared__ bf16 As[128 * 32];
  __shared__ bf16 Bs[128 * 32];
  const int t = threadIdx.x, lane = t & 63;
  const int w = t >> 6, wr = w >> 1, wc = w & 1;
  const int l15 = lane & 15, lg = lane >> 4;
  const int m0 = blockIdx.y * 128, n0 = blockIdx.x * 128;

  const int srow = t >> 2, scol = (t & 3) * 8;  // 64B/row staged by 4 lanes
  const bf16* gA0 = A + (size_t)(m0 + srow) * K + scol;
  const bf16* gA1 = A + (size_t)(m0 + 64 + srow) * K + scol;
  const bf16* gB0 = W + (size_t)(n0 + srow) * K + scol;
  const bf16* gB1 = W + (size_t)(n0 + 64 + srow) * K + scol;
  char* lA0 = (char*)As + t * 16;
  char* lA1 = (char*)As + 4096 + t * 16;
  char* lB0 = (char*)Bs + t * 16;
  char* lB1 = (char*)Bs + 4096 + t * 16;

  f32x4 acc[4][4];
#pragma unroll
  for (int i = 0; i < 4; i++)
#pragma unroll
    for (int j = 0; j < 4; j++) acc[i][j] = (f32x4){0.f, 0.f, 0.f, 0.f};

  const int tiles = K >> 5;
  for (int kt = 0; kt < tiles; ++kt) {
    __syncthreads();
    gll16(gA0, lA0); gll16(gA1, lA1);
    gll16(gB0, lB0); gll16(gB1, lB1);
    gA0 += 32; gA1 += 32; gB0 += 32; gB1 += 32;
    __syncthreads();
    bf16x8 af[4], bfv[4];
#pragma unroll
    for (int mi = 0; mi < 4; mi++)
      af[mi] = *(const bf16x8*)(As + (wr * 64 + mi * 16 + l15) * 32 + lg * 8);
#pragma unroll
    for (int ni = 0; ni < 4; ni++)
      bfv[ni] = *(const bf16x8*)(Bs + (wc * 64 + ni * 16 + l15) * 32 + lg * 8);
#pragma unroll
    for (int mi = 0; mi < 4; mi++)
#pragma unroll
      for (int ni = 0; ni < 4; ni++)
        acc[mi][ni] = MFMA_16x16x32(af[mi], bfv[ni], acc[mi][ni]);
  }

#pragma unroll
  for (int mi = 0; mi < 4; mi++) {
    const int row0 = m0 + wr * 64 + mi * 16 + lg * 4;
#pragma unroll
    for (int ni = 0; ni < 4; ni++) {
      const int col = n0 + wc * 64 + ni * 16 + l15;
      const float bc = bias[col];
#pragma unroll
      for (int r = 0; r < 4; r++) {
        float v = acc[mi][ni][r] + bc;
        if (EPI == 1) v = 0.5f * v * (1.f + erff(v * 0.70710678118f));
        const size_t idx = (size_t)(row0 + r) * N + col;
        if (EPI == 2)
          ((float*)outp)[idx] = v + resid[idx];
        else
          ((bf16*)outp)[idx] = (bf16)v;
      }
    }
  }
}

// ---------------- V transpose: vt[bh][d][s] = qkv[b,s, 2048 + h*64 + d] ----------------
__global__ __launch_bounds__(256) void vtrans_kernel(const bf16* __restrict__ qkv,
                                                     bf16* __restrict__ vt) {
  const int bh = blockIdx.y, b = bh >> 4, h = bh & 15;
  const int s0 = blockIdx.x * 128;
  const int d = threadIdx.x >> 2, sb = (threadIdx.x & 3) * 32;
  const bf16* src = qkv + (size_t)(b * 2048 + s0 + sb) * 3072 + 2048 + h * 64 + d;
  bf16* dst = vt + ((size_t)bh * 64 + d) * 2048 + s0 + sb;
#pragma unroll 8
  for (int i = 0; i < 32; i++) dst[i] = src[(size_t)i * 3072];
}

// ---------------- Flash attention (causal), bf16 in/out, fp32 softmax ----------------
// grid (S/64, B*H), 256 threads; wave w owns 16 q rows. KV tiles of 64, no block barriers.
__global__ __launch_bounds__(256) void attn_kernel(const bf16* __restrict__ qkv,
                                                   const bf16* __restrict__ vt,
                                                   bf16* __restrict__ attn_out) {
  __shared__ bf16 P[4][16 * 80];  // per-wave P tile, padded row stride 80 (160B, 16B-aligned)
  const int t = threadIdx.x, lane = t & 63, w = t >> 6;
  const int l15 = lane & 15, lg = lane >> 4;
  const int bh = blockIdx.y, b = bh >> 4, h = bh & 15;
  const int q0 = blockIdx.x * 64 + w * 16;

  const bf16* qp = qkv + (size_t)(b * 2048 + q0 + l15) * 3072 + h * 64 + lg * 8;
  const bf16x8 qf0 = *(const bf16x8*)qp;
  const bf16x8 qf1 = *(const bf16x8*)(qp + 32);
  const bf16* kbase = qkv + (size_t)(b * 2048 + l15) * 3072 + 1024 + h * 64 + lg * 8;
  const bf16* vbase = vt + ((size_t)bh * 64 + l15) * 2048 + lg * 8;
  bf16* pl = &P[w][0];

  f32x4 o[4];
#pragma unroll
  for (int dj = 0; dj < 4; dj++) o[dj] = (f32x4){0.f, 0.f, 0.f, 0.f};
  float m[4], lsum[4];
#pragma unroll
  for (int r = 0; r < 4; r++) { m[r] = -INFINITY; lsum[r] = 0.f; }

  const int kvmax = q0 + 15;
  for (int kv0 = 0; kv0 <= kvmax; kv0 += 64) {
    // QK^T: scores s[j] -> S[q=(lg*4+r)][kv=j*16+l15]
    f32x4 s[4];
#pragma unroll
    for (int j = 0; j < 4; j++) {
      const bf16* kp = kbase + (size_t)(kv0 + j * 16) * 3072;
      const bf16x8 kf0 = *(const bf16x8*)kp;
      const bf16x8 kf1 = *(const bf16x8*)(kp + 32);
      f32x4 z = (f32x4){0.f, 0.f, 0.f, 0.f};
      z = MFMA_16x16x32(qf0, kf0, z);
      z = MFMA_16x16x32(qf1, kf1, z);
      s[j] = z;
    }
    // scale + causal mask + row max
    float mx[4], alpha[4], rs[4];
#pragma unroll
    for (int r = 0; r < 4; r++) {
      const int qrow = q0 + lg * 4 + r;
      float best = -INFINITY;
#pragma unroll
      for (int j = 0; j < 4; j++) {
        float v = s[j][r] * 0.125f;
        if (kv0 + j * 16 + l15 > qrow) v = -INFINITY;
        s[j][r] = v;
        best = fmaxf(best, v);
      }
      mx[r] = best;
    }
#pragma unroll
    for (int d = 1; d < 16; d <<= 1)
#pragma unroll
      for (int r = 0; r < 4; r++) mx[r] = fmaxf(mx[r], __shfl_xor(mx[r], d));
#pragma unroll
    for (int r = 0; r < 4; r++) {
      const float mn = fmaxf(m[r], mx[r]);
      alpha[r] = __expf(m[r] - mn);
      m[r] = mn;
      rs[r] = 0.f;
    }
#pragma unroll
    for (int j = 0; j < 4; j++)
#pragma unroll
      for (int r = 0; r < 4; r++) {
        const float p = __expf(s[j][r] - m[r]);
        s[j][r] = p;
        rs[r] += p;
      }
#pragma unroll
    for (int d = 1; d < 16; d <<= 1)
#pragma unroll
      for (int r = 0; r < 4; r++) rs[r] += __shfl_xor(rs[r], d);
#pragma unroll
    for (int r = 0; r < 4; r++) lsum[r] = lsum[r] * alpha[r] + rs[r];
#pragma unroll
    for (int dj = 0; dj < 4; dj++)
#pragma unroll
      for (int r = 0; r < 4; r++) o[dj][r] *= alpha[r];
    // P -> LDS (bf16), then reread as A-fragments (transpose)
#pragma unroll
    for (int j = 0; j < 4; j++)
#pragma unroll
      for (int r = 0; r < 4; r++) pl[(lg * 4 + r) * 80 + j * 16 + l15] = (bf16)s[j][r];
    asm volatile("s_waitcnt lgkmcnt(0)" ::: "memory");
    const bf16x8 pf0 = *(const bf16x8*)(pl + l15 * 80 + lg * 8);
    const bf16x8 pf1 = *(const bf16x8*)(pl + l15 * 80 + 32 + lg * 8);
    // PV: O[q][dj*16+l15] += P @ V
#pragma unroll
    for (int dj = 0; dj < 4; dj++) {
      const bf16* vp = vbase + (size_t)dj * 16 * 2048 + kv0;
      const bf16x8 vf0 = *(const bf16x8*)vp;
      const bf16x8 vf1 = *(const bf16x8*)(vp + 32);
      o[dj] = MFMA_16x16x32(pf0, vf0, o[dj]);
      o[dj] = MFMA_16x16x32(pf1, vf1, o[dj]);
    }
  }
#pragma unroll
  for (int r = 0; r < 4; r++) lsum[r] = 1.f / lsum[r];
#pragma unroll
  for (int dj = 0; dj < 4; dj++)
#pragma unroll
    for (int r = 0; r < 4; r++)
      attn_out[(size_t)(b * 2048 + q0 + lg * 4 + r) * 1024 + h * 64 + dj * 16 + l15] =
          (bf16)(o[dj][r] * lsum[r]);
}

// ---------------- launch ----------------
extern "C" void kernel_launch(void* const* d_in, const int* in_sizes, int n_in,
                              void* d_out, int out_size, void* d_ws, size_t ws_size,
                              hipStream_t stream) {
  (void)in_sizes; (void)n_in; (void)out_size; (void)ws_size;
  const float* hidden = (const float*)d_in[0];
  const float* qkv_w  = (const float*)d_in[1];
  const float* qkv_b  = (const float*)d_in[2];
  const float* out_w  = (const float*)d_in[3];
  const float* out_b  = (const float*)d_in[4];
  const float* fc1_w  = (const float*)d_in[5];
  const float* fc1_b  = (const float*)d_in[6];
  const float* fc2_w  = (const float*)d_in[7];
  const float* fc2_b  = (const float*)d_in[8];
  const float* ln1_g  = (const float*)d_in[9];
  const float* ln1_b  = (const float*)d_in[10];
  const float* ln2_g  = (const float*)d_in[11];
  const float* ln2_b  = (const float*)d_in[12];
  float* outp = (float*)d_out;

  char* ws = (char*)d_ws;
  bf16*  ln1o = (bf16*)(ws);                            // 8 MB
  bf16*  qkvb = (bf16*)(ws + ((size_t)8 << 20));        // 24 MB
  bf16*  vtb  = (bf16*)(ws + ((size_t)32 << 20));       // 8 MB
  bf16*  atto = (bf16*)(ws + ((size_t)40 << 20));       // 8 MB
  float* res1 = (float*)(ws + ((size_t)48 << 20));      // 16 MB
  bf16*  ln2o = (bf16*)(ws + ((size_t)64 << 20));       // 8 MB
  bf16*  ff1  = (bf16*)(ws + ((size_t)72 << 20));       // 32 MB
  bf16*  wqkv = (bf16*)(ws + ((size_t)104 << 20));      // 6 MB
  bf16*  wout = (bf16*)(ws + ((size_t)110 << 20));      // 2 MB
  bf16*  wfc1 = (bf16*)(ws + ((size_t)112 << 20));      // 8 MB
  bf16*  wfc2 = (bf16*)(ws + ((size_t)120 << 20));      // 8 MB -> 128 MB total

  // weight casts
  cast_bf16_kernel<<<3072, 256, 0, stream>>>(qkv_w, wqkv, 3072 * 1024 / 4);
  cast_bf16_kernel<<<1024, 256, 0, stream>>>(out_w, wout, 1024 * 1024 / 4);
  cast_bf16_kernel<<<4096, 256, 0, stream>>>(fc1_w, wfc1, 4096 * 1024 / 4);
  cast_bf16_kernel<<<4096, 256, 0, stream>>>(fc2_w, wfc2, 4096 * 1024 / 4);

  // LN1
  ln_kernel<<<4096, 256, 0, stream>>>(hidden, ln1_g, ln1_b, ln1o);
  // QKV projection: [4096,1024] x [3072,1024]^T -> bf16 [4096,3072]
  gemm_bt<0><<<dim3(24, 32), 256, 0, stream>>>(ln1o, wqkv, qkv_b, nullptr, qkvb, 3072, 1024);
  // V transpose
  vtrans_kernel<<<dim3(16, 32), 256, 0, stream>>>(qkvb, vtb);
  // attention
  attn_kernel<<<dim3(32, 32), 256, 0, stream>>>(qkvb, vtb, atto);
  // out projection + residual -> resid1 (f32)
  gemm_bt<2><<<dim3(8, 32), 256, 0, stream>>>(atto, wout, out_b, hidden, res1, 1024, 1024);
  // LN2
  ln_kernel<<<4096, 256, 0, stream>>>(res1, ln2_g, ln2_b, ln2o);
  // FC1 + gelu -> bf16 [4096,4096]
  gemm_bt<1><<<dim3(32, 32), 256, 0, stream>>>(ln2o, wfc1, fc1_b, nullptr, ff1, 4096, 1024);
  // FC2 + residual -> d_out (f32)
  gemm_bt<2><<<dim3(8, 32), 256, 0, stream>>>(ff1, wfc2, fc2_b, res1, outp, 1024, 4096);
}

// Round 2
// 353.620 us; speedup vs baseline: 1.4082x; 1.4082x over previous
//
#include <hip/hip_runtime.h>
#include <math.h>

using bf16   = __bf16;
using bf16x8 = __attribute__((ext_vector_type(8))) __bf16;
using bf16x4 = __attribute__((ext_vector_type(4))) __bf16;
using f32x4  = __attribute__((ext_vector_type(4))) float;

#define MFMA_16x16x32(a, b, c) __builtin_amdgcn_mfma_f32_16x16x32_bf16((a), (b), (c), 0, 0, 0)

__device__ __forceinline__ void gll16(const void* g, void* l) {
  __builtin_amdgcn_global_load_lds((const __attribute__((address_space(1))) void*)g,
                                   (__attribute__((address_space(3))) void*)l,
                                   16, 0, 0);
}

// ---------------- fp32 -> bf16 cast ----------------
__global__ __launch_bounds__(256) void cast_bf16_kernel(const float* __restrict__ in,
                                                        bf16* __restrict__ out, int n4) {
  int i = blockIdx.x * 256 + threadIdx.x;
  if (i < n4) {
    float4 v = ((const float4*)in)[i];
    bf16x4 o;
    o[0] = (bf16)v.x; o[1] = (bf16)v.y; o[2] = (bf16)v.z; o[3] = (bf16)v.w;
    ((bf16x4*)out)[i] = o;
  }
}

// ---------------- LayerNorm (D=1024), fp32 in -> bf16 out ----------------
__global__ __launch_bounds__(256) void ln_kernel(const float* __restrict__ x,
                                                 const float* __restrict__ g,
                                                 const float* __restrict__ b,
                                                 bf16* __restrict__ out) {
  const int row = blockIdx.x, t = threadIdx.x;
  const float4 v = ((const float4*)(x + (size_t)row * 1024))[t];
  float s1 = v.x + v.y + v.z + v.w;
  float s2 = v.x * v.x + v.y * v.y + v.z * v.z + v.w * v.w;
#pragma unroll
  for (int d = 32; d; d >>= 1) {
    s1 += __shfl_xor(s1, d);
    s2 += __shfl_xor(s2, d);
  }
  __shared__ float red[8];
  const int w = t >> 6;
  if ((t & 63) == 0) { red[w] = s1; red[4 + w] = s2; }
  __syncthreads();
  s1 = red[0] + red[1] + red[2] + red[3];
  s2 = red[4] + red[5] + red[6] + red[7];
  const float mu = s1 * (1.f / 1024.f);
  const float rstd = rsqrtf(s2 * (1.f / 1024.f) - mu * mu + 1e-5f);
  const float4 gv = ((const float4*)g)[t];
  const float4 bv = ((const float4*)b)[t];
  bf16x4 o;
  o[0] = (bf16)((v.x - mu) * rstd * gv.x + bv.x);
  o[1] = (bf16)((v.y - mu) * rstd * gv.y + bv.y);
  o[2] = (bf16)((v.z - mu) * rstd * gv.z + bv.z);
  o[3] = (bf16)((v.w - mu) * rstd * gv.w + bv.w);
  ((bf16x4*)(out + (size_t)row * 1024))[t] = o;
}

// ---------------- GEMM: C[M,N] = A[M,K] @ W[N,K]^T (+epilogue) ----------------
// EPI 0: +bias -> bf16 out | 1: +bias, gelu(erf) -> bf16 out | 2: +bias +resid -> f32 out
template <int EPI>
__global__ __launch_bounds__(256) void gemm_bt(const bf16* __restrict__ A,
                                               const bf16* __restrict__ W,
                                               const float* __restrict__ bias,
                                               const float* __restrict__ resid,
                                               void* __restrict__ outp, int N, int K) {
  __shared__ bf16 As[128 * 32];
  __shared__ bf16 Bs[128 * 32];
  const int t = threadIdx.x, lane = t & 63;
  const int w = t >> 6, wr = w >> 1, wc = w & 1;
  const int l15 = lane & 15, lg = lane >> 4;
  const int m0 = blockIdx.y * 128, n0 = blockIdx.x * 128;

  const int srow = t >> 2, scol = (t & 3) * 8;
  const bf16* gA0 = A + (size_t)(m0 + srow) * K + scol;
  const bf16* gA1 = A + (size_t)(m0 + 64 + srow) * K + scol;
  const bf16* gB0 = W + (size_t)(n0 + srow) * K + scol;
  const bf16* gB1 = W + (size_t)(n0 + 64 + srow) * K + scol;
  char* lA0 = (char*)As + t * 16;
  char* lA1 = (char*)As + 4096 + t * 16;
  char* lB0 = (char*)Bs + t * 16;
  char* lB1 = (char*)Bs + 4096 + t * 16;

  f32x4 acc[4][4];
#pragma unroll
  for (int i = 0; i < 4; i++)
#pragma unroll
    for (int j = 0; j < 4; j++) acc[i][j] = (f32x4){0.f, 0.f, 0.f, 0.f};

  const int tiles = K >> 5;
  for (int kt = 0; kt < tiles; ++kt) {
    __syncthreads();
    gll16(gA0, lA0); gll16(gA1, lA1);
    gll16(gB0, lB0); gll16(gB1, lB1);
    gA0 += 32; gA1 += 32; gB0 += 32; gB1 += 32;
    __syncthreads();
    bf16x8 af[4], bfv[4];
#pragma unroll
    for (int mi = 0; mi < 4; mi++)
      af[mi] = *(const bf16x8*)(As + (wr * 64 + mi * 16 + l15) * 32 + lg * 8);
#pragma unroll
    for (int ni = 0; ni < 4; ni++)
      bfv[ni] = *(const bf16x8*)(Bs + (wc * 64 + ni * 16 + l15) * 32 + lg * 8);
#pragma unroll
    for (int mi = 0; mi < 4; mi++)
#pragma unroll
      for (int ni = 0; ni < 4; ni++)
        acc[mi][ni] = MFMA_16x16x32(af[mi], bfv[ni], acc[mi][ni]);
  }

#pragma unroll
  for (int mi = 0; mi < 4; mi++) {
    const int row0 = m0 + wr * 64 + mi * 16 + lg * 4;
#pragma unroll
    for (int ni = 0; ni < 4; ni++) {
      const int col = n0 + wc * 64 + ni * 16 + l15;
      const float bc = bias[col];
#pragma unroll
      for (int r = 0; r < 4; r++) {
        float v = acc[mi][ni][r] + bc;
        if (EPI == 1) v = 0.5f * v * (1.f + erff(v * 0.70710678118f));
        const size_t idx = (size_t)(row0 + r) * N + col;
        if (EPI == 2)
          ((float*)outp)[idx] = v + resid[idx];
        else
          ((bf16*)outp)[idx] = (bf16)v;
      }
    }
  }
}

// ---------------- V transpose (tiled, coalesced): vt[bh][d][s] ----------------
__global__ __launch_bounds__(256) void vtrans_kernel(const bf16* __restrict__ qkv,
                                                     bf16* __restrict__ vt) {
  __shared__ bf16 tile[64 * 80];
  const int bh = blockIdx.y, b = bh >> 4, h = bh & 15;
  const int s0 = blockIdx.x * 64;
  const int t = threadIdx.x;
#pragma unroll
  for (int c = t; c < 512; c += 256) {
    const int s = c >> 3, d0 = (c & 7) * 8;
    const bf16x8 v =
        *(const bf16x8*)(qkv + (size_t)(b * 2048 + s0 + s) * 3072 + 2048 + h * 64 + d0);
#pragma unroll
    for (int i = 0; i < 8; i++) {
      const int d = d0 + i;
      tile[d * 80 + (s ^ (8 * ((d >> 3) & 7)))] = v[i];
    }
  }
  __syncthreads();
#pragma unroll
  for (int c = t; c < 512; c += 256) {
    const int d = c >> 3, sc = (c & 7) * 8;
    const bf16x8 v = *(const bf16x8*)&tile[d * 80 + (sc ^ (8 * ((d >> 3) & 7)))];
    *(bf16x8*)(vt + ((size_t)bh * 64 + d) * 2048 + s0 + sc) = v;
  }
}

// ---------------- Flash attention (causal): block = 64 q rows, 4 waves ----------------
// K & V^T tiles (64x64 bf16) staged to LDS via global_load_lds, XOR-swizzled source,
// double-buffered. qb remapped (x+y)&31 for per-CU load balance.
__global__ __launch_bounds__(256) void attn_kernel(const bf16* __restrict__ qkv,
                                                   const bf16* __restrict__ vt,
                                                   bf16* __restrict__ attn_out) {
  __shared__ bf16 Ks[2][64 * 64];
  __shared__ bf16 Vs[2][64 * 64];
  __shared__ bf16 P[4][16 * 88];
  const int t = threadIdx.x, lane = t & 63, w = t >> 6;
  const int l15 = lane & 15, lg = lane >> 4;
  const int bh = blockIdx.y, b = bh >> 4, h = bh & 15;
  const int qb = (blockIdx.x + blockIdx.y) & 31;
  const int q0 = qb * 64 + w * 16;
  const int nt = qb + 1;

  // Q fragments (held in registers for the whole kernel)
  const bf16* qp = qkv + (size_t)(b * 2048 + q0 + l15) * 3072 + h * 64 + lg * 8;
  const bf16x8 qf0 = *(const bf16x8*)qp;
  const bf16x8 qf1 = *(const bf16x8*)(qp + 32);

  // staging: chunk i = {t, t+256}; r = i>>3 (row 0..63), c16 = i&7 (16B slot in 128B row)
  // source col pre-swizzled:  slot' = c16 ^ (r&7)  (LDS dest stays linear)
  const int r0 = t >> 3, c16 = t & 7;
  const bf16* kp0 = qkv + (size_t)(b * 2048 + r0) * 3072 + 1024 + h * 64 + 8 * (c16 ^ (r0 & 7));
  const bf16* kp1 = kp0 + (size_t)32 * 3072;  // row r0+32, same swizzle ((r+32)&7 == r&7)
  const bf16* vp0 = vt + ((size_t)bh * 64 + r0) * 2048 + 8 * (c16 ^ (r0 & 7));
  const bf16* vp1 = vp0 + (size_t)32 * 2048;

#define ATTN_STAGE(buf)                      \
  do {                                       \
    gll16(kp0, &Ks[buf][t * 8]);             \
    gll16(kp1, &Ks[buf][2048 + t * 8]);      \
    gll16(vp0, &Vs[buf][t * 8]);             \
    gll16(vp1, &Vs[buf][2048 + t * 8]);      \
    kp0 += (size_t)64 * 3072;                \
    kp1 += (size_t)64 * 3072;                \
    vp0 += 64;                               \
    vp1 += 64;                               \
  } while (0)

  bf16* pl = &P[w][0];
  f32x4 o[4];
#pragma unroll
  for (int dj = 0; dj < 4; dj++) o[dj] = (f32x4){0.f, 0.f, 0.f, 0.f};
  float m[4], lsum[4];
#pragma unroll
  for (int r = 0; r < 4; r++) { m[r] = -INFINITY; lsum[r] = 0.f; }

  ATTN_STAGE(0);
  __syncthreads();
  int cur = 0;
  for (int tt = 0; tt < nt; ++tt) {
    if (tt + 1 < nt) ATTN_STAGE(cur ^ 1);
    const int kv0 = tt * 64;
    const bf16* kb = &Ks[cur][0];
    const bf16* vb = &Vs[cur][0];

    // QK^T from LDS (swizzled read)
    f32x4 s[4];
#pragma unroll
    for (int j = 0; j < 4; j++) {
      const int rK = j * 16 + l15, sw = rK & 7;
      const bf16x8 kf0 = *(const bf16x8*)(kb + rK * 64 + 8 * (lg ^ sw));
      const bf16x8 kf1 = *(const bf16x8*)(kb + rK * 64 + 8 * ((lg + 4) ^ sw));
      f32x4 z = (f32x4){0.f, 0.f, 0.f, 0.f};
      z = MFMA_16x16x32(qf0, kf0, z);
      z = MFMA_16x16x32(qf1, kf1, z);
      s[j] = z;
    }
    // scale + causal mask + row max
    float mx[4], alpha[4], rs[4];
#pragma unroll
    for (int r = 0; r < 4; r++) {
      const int qrow = q0 + lg * 4 + r;
      float best = -INFINITY;
#pragma unroll
      for (int j = 0; j < 4; j++) {
        float v = s[j][r] * 0.125f;
        if (kv0 + j * 16 + l15 > qrow) v = -INFINITY;
        s[j][r] = v;
        best = fmaxf(best, v);
      }
      mx[r] = best;
    }
#pragma unroll
    for (int d = 1; d < 16; d <<= 1)
#pragma unroll
      for (int r = 0; r < 4; r++) mx[r] = fmaxf(mx[r], __shfl_xor(mx[r], d));
#pragma unroll
    for (int r = 0; r < 4; r++) {
      const float mn = fmaxf(m[r], mx[r]);
      alpha[r] = __expf(m[r] - mn);
      m[r] = mn;
      rs[r] = 0.f;
    }
#pragma unroll
    for (int j = 0; j < 4; j++)
#pragma unroll
      for (int r = 0; r < 4; r++) {
        const float p = __expf(s[j][r] - m[r]);
        s[j][r] = p;
        rs[r] += p;
      }
#pragma unroll
    for (int d = 1; d < 16; d <<= 1)
#pragma unroll
      for (int r = 0; r < 4; r++) rs[r] += __shfl_xor(rs[r], d);
#pragma unroll
    for (int r = 0; r < 4; r++) lsum[r] = lsum[r] * alpha[r] + rs[r];
#pragma unroll
    for (int dj = 0; dj < 4; dj++)
#pragma unroll
      for (int r = 0; r < 4; r++) o[dj][r] *= alpha[r];

    // P -> per-wave LDS (stride 88: 16B-aligned, 2-way banks), reread as A-frags
#pragma unroll
    for (int j = 0; j < 4; j++)
#pragma unroll
      for (int r = 0; r < 4; r++) pl[(lg * 4 + r) * 88 + j * 16 + l15] = (bf16)s[j][r];
    asm volatile("s_waitcnt lgkmcnt(0)" ::: "memory");
    __builtin_amdgcn_sched_barrier(0);
    const bf16x8 pf0 = *(const bf16x8*)(pl + l15 * 88 + lg * 8);
    const bf16x8 pf1 = *(const bf16x8*)(pl + l15 * 88 + 32 + lg * 8);

    // PV from LDS V^T (swizzled read)
#pragma unroll
    for (int dj = 0; dj < 4; dj++) {
      const int rV = dj * 16 + l15, sw = rV & 7;
      const bf16x8 vf0 = *(const bf16x8*)(vb + rV * 64 + 8 * (lg ^ sw));
      const bf16x8 vf1 = *(const bf16x8*)(vb + rV * 64 + 8 * ((lg + 4) ^ sw));
      o[dj] = MFMA_16x16x32(pf0, vf0, o[dj]);
      o[dj] = MFMA_16x16x32(pf1, vf1, o[dj]);
    }
    __syncthreads();
    cur ^= 1;
  }
#undef ATTN_STAGE

#pragma unroll
  for (int r = 0; r < 4; r++) lsum[r] = 1.f / lsum[r];
#pragma unroll
  for (int dj = 0; dj < 4; dj++)
#pragma unroll
    for (int r = 0; r < 4; r++)
      attn_out[(size_t)(b * 2048 + q0 + lg * 4 + r) * 1024 + h * 64 + dj * 16 + l15] =
          (bf16)(o[dj][r] * lsum[r]);
}

// ---------------- launch ----------------
extern "C" void kernel_launch(void* const* d_in, const int* in_sizes, int n_in,
                              void* d_out, int out_size, void* d_ws, size_t ws_size,
                              hipStream_t stream) {
  (void)in_sizes; (void)n_in; (void)out_size; (void)ws_size;
  const float* hidden = (const float*)d_in[0];
  const float* qkv_w  = (const float*)d_in[1];
  const float* qkv_b  = (const float*)d_in[2];
  const float* out_w  = (const float*)d_in[3];
  const float* out_b  = (const float*)d_in[4];
  const float* fc1_w  = (const float*)d_in[5];
  const float* fc1_b  = (const float*)d_in[6];
  const float* fc2_w  = (const float*)d_in[7];
  const float* fc2_b  = (const float*)d_in[8];
  const float* ln1_g  = (const float*)d_in[9];
  const float* ln1_b  = (const float*)d_in[10];
  const float* ln2_g  = (const float*)d_in[11];
  const float* ln2_b  = (const float*)d_in[12];
  float* outp = (float*)d_out;

  char* ws = (char*)d_ws;
  bf16*  ln1o = (bf16*)(ws);                            // 8 MB
  bf16*  qkvb = (bf16*)(ws + ((size_t)8 << 20));        // 24 MB
  bf16*  vtb  = (bf16*)(ws + ((size_t)32 << 20));       // 8 MB
  bf16*  atto = (bf16*)(ws + ((size_t)40 << 20));       // 8 MB
  float* res1 = (float*)(ws + ((size_t)48 << 20));      // 16 MB
  bf16*  ln2o = (bf16*)(ws + ((size_t)64 << 20));       // 8 MB
  bf16*  ff1  = (bf16*)(ws + ((size_t)72 << 20));       // 32 MB
  bf16*  wqkv = (bf16*)(ws + ((size_t)104 << 20));      // 6 MB
  bf16*  wout = (bf16*)(ws + ((size_t)110 << 20));      // 2 MB
  bf16*  wfc1 = (bf16*)(ws + ((size_t)112 << 20));      // 8 MB
  bf16*  wfc2 = (bf16*)(ws + ((size_t)120 << 20));      // 8 MB

  cast_bf16_kernel<<<3072, 256, 0, stream>>>(qkv_w, wqkv, 3072 * 1024 / 4);
  cast_bf16_kernel<<<1024, 256, 0, stream>>>(out_w, wout, 1024 * 1024 / 4);
  cast_bf16_kernel<<<4096, 256, 0, stream>>>(fc1_w, wfc1, 4096 * 1024 / 4);
  cast_bf16_kernel<<<4096, 256, 0, stream>>>(fc2_w, wfc2, 4096 * 1024 / 4);

  ln_kernel<<<4096, 256, 0, stream>>>(hidden, ln1_g, ln1_b, ln1o);
  gemm_bt<0><<<dim3(24, 32), 256, 0, stream>>>(ln1o, wqkv, qkv_b, nullptr, qkvb, 3072, 1024);
  vtrans_kernel<<<dim3(32, 32), 256, 0, stream>>>(qkvb, vtb);
  attn_kernel<<<dim3(32, 32), 256, 0, stream>>>(qkvb, vtb, atto);
  gemm_bt<2><<<dim3(8, 32), 256, 0, stream>>>(atto, wout, out_b, hidden, res1, 1024, 1024);
  ln_kernel<<<4096, 256, 0, stream>>>(res1, ln2_g, ln2_b, ln2o);
  gemm_bt<1><<<dim3(32, 32), 256, 0, stream>>>(ln2o, wfc1, fc1_b, nullptr, ff1, 4096, 1024);
  gemm_bt<2><<<dim3(8, 32), 256, 0, stream>>>(ff1, wfc2, fc2_b, res1, outp, 1024, 4096);
}

// Round 3
// 338.315 us; speedup vs baseline: 1.4720x; 1.0452x over previous
//
#include <hip/hip_runtime.h>
#include <math.h>

using bf16   = __bf16;
using bf16x8 = __attribute__((ext_vector_type(8))) __bf16;
using bf16x4 = __attribute__((ext_vector_type(4))) __bf16;
using f32x4  = __attribute__((ext_vector_type(4))) float;

#define MFMA_16x16x32(a, b, c) __builtin_amdgcn_mfma_f32_16x16x32_bf16((a), (b), (c), 0, 0, 0)

__device__ __forceinline__ void gll16(const void* g, void* l) {
  __builtin_amdgcn_global_load_lds((const __attribute__((address_space(1))) void*)g,
                                   (__attribute__((address_space(3))) void*)l,
                                   16, 0, 0);
}

// ---------------- fp32 -> bf16 cast ----------------
__global__ __launch_bounds__(256) void cast_bf16_kernel(const float* __restrict__ in,
                                                        bf16* __restrict__ out, int n4) {
  int i = blockIdx.x * 256 + threadIdx.x;
  if (i < n4) {
    float4 v = ((const float4*)in)[i];
    bf16x4 o;
    o[0] = (bf16)v.x; o[1] = (bf16)v.y; o[2] = (bf16)v.z; o[3] = (bf16)v.w;
    ((bf16x4*)out)[i] = o;
  }
}

// ---------------- LayerNorm (D=1024), fp32 in -> bf16 out ----------------
__global__ __launch_bounds__(256) void ln_kernel(const float* __restrict__ x,
                                                 const float* __restrict__ g,
                                                 const float* __restrict__ b,
                                                 bf16* __restrict__ out) {
  const int row = blockIdx.x, t = threadIdx.x;
  const float4 v = ((const float4*)(x + (size_t)row * 1024))[t];
  float s1 = v.x + v.y + v.z + v.w;
  float s2 = v.x * v.x + v.y * v.y + v.z * v.z + v.w * v.w;
#pragma unroll
  for (int d = 32; d; d >>= 1) {
    s1 += __shfl_xor(s1, d);
    s2 += __shfl_xor(s2, d);
  }
  __shared__ float red[8];
  const int w = t >> 6;
  if ((t & 63) == 0) { red[w] = s1; red[4 + w] = s2; }
  __syncthreads();
  s1 = red[0] + red[1] + red[2] + red[3];
  s2 = red[4] + red[5] + red[6] + red[7];
  const float mu = s1 * (1.f / 1024.f);
  const float rstd = rsqrtf(s2 * (1.f / 1024.f) - mu * mu + 1e-5f);
  const float4 gv = ((const float4*)g)[t];
  const float4 bv = ((const float4*)b)[t];
  bf16x4 o;
  o[0] = (bf16)((v.x - mu) * rstd * gv.x + bv.x);
  o[1] = (bf16)((v.y - mu) * rstd * gv.y + bv.y);
  o[2] = (bf16)((v.z - mu) * rstd * gv.z + bv.z);
  o[3] = (bf16)((v.w - mu) * rstd * gv.w + bv.w);
  ((bf16x4*)(out + (size_t)row * 1024))[t] = o;
}

// ============ 256x256 8-phase GEMM (T2+T3+T4+T5): C = A[M,K] @ W[N,K]^T ============
// EPI 0: +bias -> bf16 | 1: +bias, gelu -> bf16.  512 thr (2Mx4N waves), BK=64,
// 128KB LDS dbuf, st_16x32 swizzle (byte ^= ((byte>>9)&1)<<5), raw barriers,
// counted vmcnt once per K-tile, setprio around MFMA clusters.
template <int EPI>
__global__ __launch_bounds__(512, 2) void gemm256(const bf16* __restrict__ A,
                                                  const bf16* __restrict__ W,
                                                  const float* __restrict__ bias,
                                                  bf16* __restrict__ outp, int N, int K,
                                                  int nbx) {
  __shared__ __align__(1024) bf16 lds[65536];  // [db][op][half][8192] = 128 KB
  const int t = threadIdx.x, lane = t & 63, w = t >> 6;
  const int wm = w >> 2, wn = w & 3;
  const int l15 = lane & 15, lg = lane >> 4;

  // bijective XCD swizzle (nwg % 8 == 0 for all our grids)
  const int nwg = gridDim.x, cpx = nwg >> 3, bid = blockIdx.x;
  const int swz = (bid & 7) * cpx + (bid >> 3);
  const int bx = swz % nbx, by = swz / nbx;
  const int m0 = by * 256, n0 = bx * 256;

  // staging: 8 units = {A,B} x {half0,half1} x {slot t, t+512}; LDS dest linear,
  // global source pre-swizzled (inverse st_16x32, an involution).
  const bf16* src[8];
  int dst[8];
  {
    const int ss[2] = {t, t + 512};
#pragma unroll
    for (int i = 0; i < 2; i++) {
      const int d = ss[i] * 16;
      const int L = d ^ (((d >> 9) & 1) << 5);
      const int r = L >> 7, coff = (L & 127) >> 1;
#pragma unroll
      for (int hf = 0; hf < 2; hf++) {
        src[hf * 2 + i]     = A + (size_t)(m0 + hf * 128 + r) * K + coff;
        src[4 + hf * 2 + i] = W + (size_t)(n0 + hf * 128 + r) * K + coff;
        dst[hf * 2 + i]     = hf * 8192 + ss[i] * 8;
        dst[4 + hf * 2 + i] = 16384 + hf * 8192 + ss[i] * 8;
      }
    }
  }

#define STAGE256(db_)                                   \
  do {                                                  \
    _Pragma("unroll") for (int u = 0; u < 8; u++) {     \
      gll16(src[u], lds + (db_)*32768 + dst[u]);        \
      src[u] += 64;                                     \
    }                                                   \
  } while (0)

  f32x4 acc[8][4];
#pragma unroll
  for (int mi = 0; mi < 8; mi++)
#pragma unroll
    for (int ni = 0; ni < 4; ni++) acc[mi][ni] = (f32x4){0.f, 0.f, 0.f, 0.f};

  const int ntiles = K >> 6;
  STAGE256(0);
  asm volatile("s_waitcnt vmcnt(0)" ::: "memory");
  __builtin_amdgcn_s_barrier();

  for (int kt = 0; kt < ntiles; ++kt) {
    const int db = kt & 1;
    const bf16* Ab = lds + db * 32768 + wm * 8192;
    const bf16* Bb = lds + db * 32768 + 16384 + (wn >> 1) * 8192;
    bf16x8 bfr[4][2];
#pragma unroll
    for (int p = 0; p < 4; ++p) {
      bf16x8 af[2][2];
#pragma unroll
      for (int mi2 = 0; mi2 < 2; ++mi2)
#pragma unroll
        for (int ks = 0; ks < 2; ++ks) {
          const int row = (2 * p + mi2) * 16 + l15;
          const int Pb = (row * 128 + ks * 64 + lg * 16) ^ (((row >> 2) & 1) << 5);
          af[mi2][ks] = *(const bf16x8*)((const char*)Ab + Pb);
        }
      if (p == 0) {
#pragma unroll
        for (int ni = 0; ni < 4; ++ni)
#pragma unroll
          for (int ks = 0; ks < 2; ++ks) {
            const int row = (wn & 1) * 64 + ni * 16 + l15;
            const int Pb = (row * 128 + ks * 64 + lg * 16) ^ (((row >> 2) & 1) << 5);
            bfr[ni][ks] = *(const bf16x8*)((const char*)Bb + Pb);
          }
        if (kt + 1 < ntiles) STAGE256(db ^ 1);
      }
      __builtin_amdgcn_s_barrier();
      asm volatile("s_waitcnt lgkmcnt(0)" ::: "memory");
      __builtin_amdgcn_sched_barrier(0);
      __builtin_amdgcn_s_setprio(1);
#pragma unroll
      for (int ks = 0; ks < 2; ++ks)
#pragma unroll
        for (int ni = 0; ni < 4; ++ni) {
          acc[2 * p][ni] = MFMA_16x16x32(af[0][ks], bfr[ni][ks], acc[2 * p][ni]);
          acc[2 * p + 1][ni] = MFMA_16x16x32(af[1][ks], bfr[ni][ks], acc[2 * p + 1][ni]);
        }
      __builtin_amdgcn_s_setprio(0);
      if (p == 3) asm volatile("s_waitcnt vmcnt(0)" ::: "memory");
      __builtin_amdgcn_s_barrier();
    }
  }
#undef STAGE256

#pragma unroll
  for (int mi = 0; mi < 8; ++mi) {
    const int row0 = m0 + wm * 128 + mi * 16 + lg * 4;
#pragma unroll
    for (int ni = 0; ni < 4; ++ni) {
      const int col = n0 + wn * 64 + ni * 16 + l15;
      const float bc = bias[col];
#pragma unroll
      for (int r = 0; r < 4; ++r) {
        float v = acc[mi][ni][r] + bc;
        if (EPI == 1) v = 0.5f * v * (1.f + erff(v * 0.70710678118f));
        outp[(size_t)(row0 + r) * N + col] = (bf16)v;
      }
    }
  }
}

// ---------------- 128x128 GEMM (m97 structure): +bias +resid -> f32 out ----------------
__global__ __launch_bounds__(256) void gemm_bt2(const bf16* __restrict__ A,
                                                const bf16* __restrict__ W,
                                                const float* __restrict__ bias,
                                                const float* __restrict__ resid,
                                                float* __restrict__ outp, int N, int K) {
  __shared__ bf16 As[128 * 32];
  __shared__ bf16 Bs[128 * 32];
  const int t = threadIdx.x, lane = t & 63;
  const int w = t >> 6, wr = w >> 1, wc = w & 1;
  const int l15 = lane & 15, lg = lane >> 4;
  const int m0 = blockIdx.y * 128, n0 = blockIdx.x * 128;

  const int srow = t >> 2, scol = (t & 3) * 8;
  const bf16* gA0 = A + (size_t)(m0 + srow) * K + scol;
  const bf16* gA1 = A + (size_t)(m0 + 64 + srow) * K + scol;
  const bf16* gB0 = W + (size_t)(n0 + srow) * K + scol;
  const bf16* gB1 = W + (size_t)(n0 + 64 + srow) * K + scol;
  char* lA0 = (char*)As + t * 16;
  char* lA1 = (char*)As + 4096 + t * 16;
  char* lB0 = (char*)Bs + t * 16;
  char* lB1 = (char*)Bs + 4096 + t * 16;

  f32x4 acc[4][4];
#pragma unroll
  for (int i = 0; i < 4; i++)
#pragma unroll
    for (int j = 0; j < 4; j++) acc[i][j] = (f32x4){0.f, 0.f, 0.f, 0.f};

  const int tiles = K >> 5;
  for (int kt = 0; kt < tiles; ++kt) {
    __syncthreads();
    gll16(gA0, lA0); gll16(gA1, lA1);
    gll16(gB0, lB0); gll16(gB1, lB1);
    gA0 += 32; gA1 += 32; gB0 += 32; gB1 += 32;
    __syncthreads();
    bf16x8 af[4], bfv[4];
#pragma unroll
    for (int mi = 0; mi < 4; mi++)
      af[mi] = *(const bf16x8*)(As + (wr * 64 + mi * 16 + l15) * 32 + lg * 8);
#pragma unroll
    for (int ni = 0; ni < 4; ni++)
      bfv[ni] = *(const bf16x8*)(Bs + (wc * 64 + ni * 16 + l15) * 32 + lg * 8);
#pragma unroll
    for (int mi = 0; mi < 4; mi++)
#pragma unroll
      for (int ni = 0; ni < 4; ni++)
        acc[mi][ni] = MFMA_16x16x32(af[mi], bfv[ni], acc[mi][ni]);
  }

#pragma unroll
  for (int mi = 0; mi < 4; mi++) {
    const int row0 = m0 + wr * 64 + mi * 16 + lg * 4;
#pragma unroll
    for (int ni = 0; ni < 4; ni++) {
      const int col = n0 + wc * 64 + ni * 16 + l15;
      const float bc = bias[col];
#pragma unroll
      for (int r = 0; r < 4; r++) {
        const size_t idx = (size_t)(row0 + r) * N + col;
        outp[idx] = acc[mi][ni][r] + bc + resid[idx];
      }
    }
  }
}

// ---------------- V transpose (tiled, coalesced): vt[bh][d][s] ----------------
__global__ __launch_bounds__(256) void vtrans_kernel(const bf16* __restrict__ qkv,
                                                     bf16* __restrict__ vt) {
  __shared__ bf16 tile[64 * 80];
  const int bh = blockIdx.y, b = bh >> 4, h = bh & 15;
  const int s0 = blockIdx.x * 64;
  const int t = threadIdx.x;
#pragma unroll
  for (int c = t; c < 512; c += 256) {
    const int s = c >> 3, d0 = (c & 7) * 8;
    const bf16x8 v =
        *(const bf16x8*)(qkv + (size_t)(b * 2048 + s0 + s) * 3072 + 2048 + h * 64 + d0);
#pragma unroll
    for (int i = 0; i < 8; i++) {
      const int d = d0 + i;
      tile[d * 80 + (s ^ (8 * ((d >> 3) & 7)))] = v[i];
    }
  }
  __syncthreads();
#pragma unroll
  for (int c = t; c < 512; c += 256) {
    const int d = c >> 3, sc = (c & 7) * 8;
    const bf16x8 v = *(const bf16x8*)&tile[d * 80 + (sc ^ (8 * ((d >> 3) & 7)))];
    *(bf16x8*)(vt + ((size_t)bh * 64 + d) * 2048 + s0 + sc) = v;
  }
}

// ---------------- Flash attention (causal): block = 64 q rows, 4 waves ----------------
__global__ __launch_bounds__(256) void attn_kernel(const bf16* __restrict__ qkv,
                                                   const bf16* __restrict__ vt,
                                                   bf16* __restrict__ attn_out) {
  __shared__ bf16 Ks[2][64 * 64];
  __shared__ bf16 Vs[2][64 * 64];
  __shared__ bf16 P[4][16 * 88];
  const int t = threadIdx.x, lane = t & 63, w = t >> 6;
  const int l15 = lane & 15, lg = lane >> 4;
  const int bh = blockIdx.y, b = bh >> 4, h = bh & 15;
  const int qb = (blockIdx.x + blockIdx.y) & 31;
  const int q0 = qb * 64 + w * 16;
  const int nt = qb + 1;

  const bf16* qp = qkv + (size_t)(b * 2048 + q0 + l15) * 3072 + h * 64 + lg * 8;
  const bf16x8 qf0 = *(const bf16x8*)qp;
  const bf16x8 qf1 = *(const bf16x8*)(qp + 32);

  const int r0 = t >> 3, c16 = t & 7;
  const bf16* kp0 = qkv + (size_t)(b * 2048 + r0) * 3072 + 1024 + h * 64 + 8 * (c16 ^ (r0 & 7));
  const bf16* kp1 = kp0 + (size_t)32 * 3072;
  const bf16* vp0 = vt + ((size_t)bh * 64 + r0) * 2048 + 8 * (c16 ^ (r0 & 7));
  const bf16* vp1 = vp0 + (size_t)32 * 2048;

#define ATTN_STAGE(buf)                      \
  do {                                       \
    gll16(kp0, &Ks[buf][t * 8]);             \
    gll16(kp1, &Ks[buf][2048 + t * 8]);      \
    gll16(vp0, &Vs[buf][t * 8]);             \
    gll16(vp1, &Vs[buf][2048 + t * 8]);      \
    kp0 += (size_t)64 * 3072;                \
    kp1 += (size_t)64 * 3072;                \
    vp0 += 64;                               \
    vp1 += 64;                               \
  } while (0)

  bf16* pl = &P[w][0];
  f32x4 o[4];
#pragma unroll
  for (int dj = 0; dj < 4; dj++) o[dj] = (f32x4){0.f, 0.f, 0.f, 0.f};
  float m[4], lsum[4];
#pragma unroll
  for (int r = 0; r < 4; r++) { m[r] = -INFINITY; lsum[r] = 0.f; }

  ATTN_STAGE(0);
  __syncthreads();
  int cur = 0;
  for (int tt = 0; tt < nt; ++tt) {
    if (tt + 1 < nt) ATTN_STAGE(cur ^ 1);
    const int kv0 = tt * 64;
    const bf16* kb = &Ks[cur][0];
    const bf16* vb = &Vs[cur][0];

    f32x4 s[4];
#pragma unroll
    for (int j = 0; j < 4; j++) {
      const int rK = j * 16 + l15, sw = rK & 7;
      const bf16x8 kf0 = *(const bf16x8*)(kb + rK * 64 + 8 * (lg ^ sw));
      const bf16x8 kf1 = *(const bf16x8*)(kb + rK * 64 + 8 * ((lg + 4) ^ sw));
      f32x4 z = (f32x4){0.f, 0.f, 0.f, 0.f};
      z = MFMA_16x16x32(qf0, kf0, z);
      z = MFMA_16x16x32(qf1, kf1, z);
      s[j] = z;
    }
    float mx[4], alpha[4], rs[4];
#pragma unroll
    for (int r = 0; r < 4; r++) {
      const int qrow = q0 + lg * 4 + r;
      float best = -INFINITY;
#pragma unroll
      for (int j = 0; j < 4; j++) {
        float v = s[j][r] * 0.125f;
        if (kv0 + j * 16 + l15 > qrow) v = -INFINITY;
        s[j][r] = v;
        best = fmaxf(best, v);
      }
      mx[r] = best;
    }
#pragma unroll
    for (int d = 1; d < 16; d <<= 1)
#pragma unroll
      for (int r = 0; r < 4; r++) mx[r] = fmaxf(mx[r], __shfl_xor(mx[r], d));
#pragma unroll
    for (int r = 0; r < 4; r++) {
      const float mn = fmaxf(m[r], mx[r]);
      alpha[r] = __expf(m[r] - mn);
      m[r] = mn;
      rs[r] = 0.f;
    }
#pragma unroll
    for (int j = 0; j < 4; j++)
#pragma unroll
      for (int r = 0; r < 4; r++) {
        const float p = __expf(s[j][r] - m[r]);
        s[j][r] = p;
        rs[r] += p;
      }
#pragma unroll
    for (int d = 1; d < 16; d <<= 1)
#pragma unroll
      for (int r = 0; r < 4; r++) rs[r] += __shfl_xor(rs[r], d);
#pragma unroll
    for (int r = 0; r < 4; r++) lsum[r] = lsum[r] * alpha[r] + rs[r];
#pragma unroll
    for (int dj = 0; dj < 4; dj++)
#pragma unroll
      for (int r = 0; r < 4; r++) o[dj][r] *= alpha[r];

#pragma unroll
    for (int j = 0; j < 4; j++)
#pragma unroll
      for (int r = 0; r < 4; r++) pl[(lg * 4 + r) * 88 + j * 16 + l15] = (bf16)s[j][r];
    asm volatile("s_waitcnt lgkmcnt(0)" ::: "memory");
    __builtin_amdgcn_sched_barrier(0);
    const bf16x8 pf0 = *(const bf16x8*)(pl + l15 * 88 + lg * 8);
    const bf16x8 pf1 = *(const bf16x8*)(pl + l15 * 88 + 32 + lg * 8);

#pragma unroll
    for (int dj = 0; dj < 4; dj++) {
      const int rV = dj * 16 + l15, sw = rV & 7;
      const bf16x8 vf0 = *(const bf16x8*)(vb + rV * 64 + 8 * (lg ^ sw));
      const bf16x8 vf1 = *(const bf16x8*)(vb + rV * 64 + 8 * ((lg + 4) ^ sw));
      o[dj] = MFMA_16x16x32(pf0, vf0, o[dj]);
      o[dj] = MFMA_16x16x32(pf1, vf1, o[dj]);
    }
    __syncthreads();
    cur ^= 1;
  }
#undef ATTN_STAGE

#pragma unroll
  for (int r = 0; r < 4; r++) lsum[r] = 1.f / lsum[r];
#pragma unroll
  for (int dj = 0; dj < 4; dj++)
#pragma unroll
    for (int r = 0; r < 4; r++)
      attn_out[(size_t)(b * 2048 + q0 + lg * 4 + r) * 1024 + h * 64 + dj * 16 + l15] =
          (bf16)(o[dj][r] * lsum[r]);
}

// ---------------- launch ----------------
extern "C" void kernel_launch(void* const* d_in, const int* in_sizes, int n_in,
                              void* d_out, int out_size, void* d_ws, size_t ws_size,
                              hipStream_t stream) {
  (void)in_sizes; (void)n_in; (void)out_size; (void)ws_size;
  const float* hidden = (const float*)d_in[0];
  const float* qkv_w  = (const float*)d_in[1];
  const float* qkv_b  = (const float*)d_in[2];
  const float* out_w  = (const float*)d_in[3];
  const float* out_b  = (const float*)d_in[4];
  const float* fc1_w  = (const float*)d_in[5];
  const float* fc1_b  = (const float*)d_in[6];
  const float* fc2_w  = (const float*)d_in[7];
  const float* fc2_b  = (const float*)d_in[8];
  const float* ln1_g  = (const float*)d_in[9];
  const float* ln1_b  = (const float*)d_in[10];
  const float* ln2_g  = (const float*)d_in[11];
  const float* ln2_b  = (const float*)d_in[12];
  float* outp = (float*)d_out;

  char* ws = (char*)d_ws;
  bf16*  ln1o = (bf16*)(ws);
  bf16*  qkvb = (bf16*)(ws + ((size_t)8 << 20));
  bf16*  vtb  = (bf16*)(ws + ((size_t)32 << 20));
  bf16*  atto = (bf16*)(ws + ((size_t)40 << 20));
  float* res1 = (float*)(ws + ((size_t)48 << 20));
  bf16*  ln2o = (bf16*)(ws + ((size_t)64 << 20));
  bf16*  ff1  = (bf16*)(ws + ((size_t)72 << 20));
  bf16*  wqkv = (bf16*)(ws + ((size_t)104 << 20));
  bf16*  wout = (bf16*)(ws + ((size_t)110 << 20));
  bf16*  wfc1 = (bf16*)(ws + ((size_t)112 << 20));
  bf16*  wfc2 = (bf16*)(ws + ((size_t)120 << 20));

  cast_bf16_kernel<<<3072, 256, 0, stream>>>(qkv_w, wqkv, 3072 * 1024 / 4);
  cast_bf16_kernel<<<1024, 256, 0, stream>>>(out_w, wout, 1024 * 1024 / 4);
  cast_bf16_kernel<<<4096, 256, 0, stream>>>(fc1_w, wfc1, 4096 * 1024 / 4);
  cast_bf16_kernel<<<4096, 256, 0, stream>>>(fc2_w, wfc2, 4096 * 1024 / 4);

  ln_kernel<<<4096, 256, 0, stream>>>(hidden, ln1_g, ln1_b, ln1o);
  // QKV: [4096,1024] x [3072,1024]^T, 256^2 8-phase, grid 12x16=192
  gemm256<0><<<192, 512, 0, stream>>>(ln1o, wqkv, qkv_b, qkvb, 3072, 1024, 12);
  vtrans_kernel<<<dim3(32, 32), 256, 0, stream>>>(qkvb, vtb);
  attn_kernel<<<dim3(32, 32), 256, 0, stream>>>(qkvb, vtb, atto);
  gemm_bt2<<<dim3(8, 32), 256, 0, stream>>>(atto, wout, out_b, hidden, res1, 1024, 1024);
  ln_kernel<<<4096, 256, 0, stream>>>(res1, ln2_g, ln2_b, ln2o);
  // FC1: [4096,1024] x [4096,1024]^T + gelu, grid 16x16=256
  gemm256<1><<<256, 512, 0, stream>>>(ln2o, wfc1, fc1_b, ff1, 4096, 1024, 16);
  gemm_bt2<<<dim3(8, 32), 256, 0, stream>>>(ff1, wfc2, fc2_b, res1, outp, 1024, 4096);
}

// Round 4
// 310.141 us; speedup vs baseline: 1.6057x; 1.0908x over previous
//
#include <hip/hip_runtime.h>
#include <math.h>

using bf16   = __bf16;
using bf16x8 = __attribute__((ext_vector_type(8))) __bf16;
using bf16x4 = __attribute__((ext_vector_type(4))) __bf16;
using f32x4  = __attribute__((ext_vector_type(4))) float;
using f32x16 = __attribute__((ext_vector_type(16))) float;

#define MFMA_16x16x32(a, b, c) __builtin_amdgcn_mfma_f32_16x16x32_bf16((a), (b), (c), 0, 0, 0)
#define MFMA32(a, b, c) __builtin_amdgcn_mfma_f32_32x32x16_bf16((a), (b), (c), 0, 0, 0)

__device__ __forceinline__ void gll16(const void* g, void* l) {
  __builtin_amdgcn_global_load_lds((const __attribute__((address_space(1))) void*)g,
                                   (__attribute__((address_space(3))) void*)l,
                                   16, 0, 0);
}

__device__ __forceinline__ int cvtpk(float lo, float hi) {
  int r;
  asm("v_cvt_pk_bf16_f32 %0, %1, %2" : "=v"(r) : "v"(lo), "v"(hi));
  return r;
}

// ---------------- fused fp32 -> bf16 weight casts ----------------
__global__ __launch_bounds__(256) void cast4_kernel(const float* __restrict__ s0, bf16* d0,
                                                    const float* __restrict__ s1, bf16* d1,
                                                    const float* __restrict__ s2, bf16* d2,
                                                    const float* __restrict__ s3, bf16* d3) {
  int i = blockIdx.x * 256 + threadIdx.x;  // in float4 units
  const float* s;
  bf16* d;
  if (i < 786432) { s = s0; d = d0; }
  else if (i < 1048576) { s = s1; d = d1; i -= 786432; }
  else if (i < 2097152) { s = s2; d = d2; i -= 1048576; }
  else { s = s3; d = d3; i -= 2097152; }
  float4 v = ((const float4*)s)[i];
  bf16x4 o;
  o[0] = (bf16)v.x; o[1] = (bf16)v.y; o[2] = (bf16)v.z; o[3] = (bf16)v.w;
  ((bf16x4*)d)[i] = o;
}

// ---------------- LayerNorm (D=1024), fp32 in -> bf16 out ----------------
__global__ __launch_bounds__(256) void ln_kernel(const float* __restrict__ x,
                                                 const float* __restrict__ g,
                                                 const float* __restrict__ b,
                                                 bf16* __restrict__ out) {
  const int row = blockIdx.x, t = threadIdx.x;
  const float4 v = ((const float4*)(x + (size_t)row * 1024))[t];
  float s1 = v.x + v.y + v.z + v.w;
  float s2 = v.x * v.x + v.y * v.y + v.z * v.z + v.w * v.w;
#pragma unroll
  for (int d = 32; d; d >>= 1) {
    s1 += __shfl_xor(s1, d);
    s2 += __shfl_xor(s2, d);
  }
  __shared__ float red[8];
  const int w = t >> 6;
  if ((t & 63) == 0) { red[w] = s1; red[4 + w] = s2; }
  __syncthreads();
  s1 = red[0] + red[1] + red[2] + red[3];
  s2 = red[4] + red[5] + red[6] + red[7];
  const float mu = s1 * (1.f / 1024.f);
  const float rstd = rsqrtf(s2 * (1.f / 1024.f) - mu * mu + 1e-5f);
  const float4 gv = ((const float4*)g)[t];
  const float4 bv = ((const float4*)b)[t];
  bf16x4 o;
  o[0] = (bf16)((v.x - mu) * rstd * gv.x + bv.x);
  o[1] = (bf16)((v.y - mu) * rstd * gv.y + bv.y);
  o[2] = (bf16)((v.z - mu) * rstd * gv.z + bv.z);
  o[3] = (bf16)((v.w - mu) * rstd * gv.w + bv.w);
  ((bf16x4*)(out + (size_t)row * 1024))[t] = o;
}

// ============ 256x256 8-phase GEMM: C = A[M,K] @ W[N,K]^T ============
template <int EPI>
__global__ __launch_bounds__(512, 2) void gemm256(const bf16* __restrict__ A,
                                                  const bf16* __restrict__ W,
                                                  const float* __restrict__ bias,
                                                  bf16* __restrict__ outp, int N, int K,
                                                  int nbx) {
  __shared__ __align__(1024) bf16 lds[65536];
  const int t = threadIdx.x, lane = t & 63, w = t >> 6;
  const int wm = w >> 2, wn = w & 3;
  const int l15 = lane & 15, lg = lane >> 4;

  const int nwg = gridDim.x, cpx = nwg >> 3, bid = blockIdx.x;
  const int swz = (bid & 7) * cpx + (bid >> 3);
  const int bx = swz % nbx, by = swz / nbx;
  const int m0 = by * 256, n0 = bx * 256;

  const bf16* src[8];
  int dst[8];
  {
    const int ss[2] = {t, t + 512};
#pragma unroll
    for (int i = 0; i < 2; i++) {
      const int d = ss[i] * 16;
      const int L = d ^ (((d >> 9) & 1) << 5);
      const int r = L >> 7, coff = (L & 127) >> 1;
#pragma unroll
      for (int hf = 0; hf < 2; hf++) {
        src[hf * 2 + i]     = A + (size_t)(m0 + hf * 128 + r) * K + coff;
        src[4 + hf * 2 + i] = W + (size_t)(n0 + hf * 128 + r) * K + coff;
        dst[hf * 2 + i]     = hf * 8192 + ss[i] * 8;
        dst[4 + hf * 2 + i] = 16384 + hf * 8192 + ss[i] * 8;
      }
    }
  }

#define STAGE256(db_)                                   \
  do {                                                  \
    _Pragma("unroll") for (int u = 0; u < 8; u++) {     \
      gll16(src[u], lds + (db_)*32768 + dst[u]);        \
      src[u] += 64;                                     \
    }                                                   \
  } while (0)

  f32x4 acc[8][4];
#pragma unroll
  for (int mi = 0; mi < 8; mi++)
#pragma unroll
    for (int ni = 0; ni < 4; ni++) acc[mi][ni] = (f32x4){0.f, 0.f, 0.f, 0.f};

  const int ntiles = K >> 6;
  STAGE256(0);
  asm volatile("s_waitcnt vmcnt(0)" ::: "memory");
  __builtin_amdgcn_s_barrier();

  for (int kt = 0; kt < ntiles; ++kt) {
    const int db = kt & 1;
    const bf16* Ab = lds + db * 32768 + wm * 8192;
    const bf16* Bb = lds + db * 32768 + 16384 + (wn >> 1) * 8192;
    bf16x8 bfr[4][2];
#pragma unroll
    for (int p = 0; p < 4; ++p) {
      bf16x8 af[2][2];
#pragma unroll
      for (int mi2 = 0; mi2 < 2; ++mi2)
#pragma unroll
        for (int ks = 0; ks < 2; ++ks) {
          const int row = (2 * p + mi2) * 16 + l15;
          const int Pb = (row * 128 + ks * 64 + lg * 16) ^ (((row >> 2) & 1) << 5);
          af[mi2][ks] = *(const bf16x8*)((const char*)Ab + Pb);
        }
      if (p == 0) {
#pragma unroll
        for (int ni = 0; ni < 4; ++ni)
#pragma unroll
          for (int ks = 0; ks < 2; ++ks) {
            const int row = (wn & 1) * 64 + ni * 16 + l15;
            const int Pb = (row * 128 + ks * 64 + lg * 16) ^ (((row >> 2) & 1) << 5);
            bfr[ni][ks] = *(const bf16x8*)((const char*)Bb + Pb);
          }
        if (kt + 1 < ntiles) STAGE256(db ^ 1);
      }
      __builtin_amdgcn_s_barrier();
      asm volatile("s_waitcnt lgkmcnt(0)" ::: "memory");
      __builtin_amdgcn_sched_barrier(0);
      __builtin_amdgcn_s_setprio(1);
#pragma unroll
      for (int ks = 0; ks < 2; ++ks)
#pragma unroll
        for (int ni = 0; ni < 4; ++ni) {
          acc[2 * p][ni] = MFMA_16x16x32(af[0][ks], bfr[ni][ks], acc[2 * p][ni]);
          acc[2 * p + 1][ni] = MFMA_16x16x32(af[1][ks], bfr[ni][ks], acc[2 * p + 1][ni]);
        }
      __builtin_amdgcn_s_setprio(0);
      if (p == 3) asm volatile("s_waitcnt vmcnt(0)" ::: "memory");
      __builtin_amdgcn_s_barrier();
    }
  }
#undef STAGE256

#pragma unroll
  for (int mi = 0; mi < 8; ++mi) {
    const int row0 = m0 + wm * 128 + mi * 16 + lg * 4;
#pragma unroll
    for (int ni = 0; ni < 4; ++ni) {
      const int col = n0 + wn * 64 + ni * 16 + l15;
      const float bc = bias[col];
#pragma unroll
      for (int r = 0; r < 4; ++r) {
        float v = acc[mi][ni][r] + bc;
        if (EPI == 1) v = 0.5f * v * (1.f + erff(v * 0.70710678118f));
        outp[(size_t)(row0 + r) * N + col] = (bf16)v;
      }
    }
  }
}

// ---------------- 128x128 GEMM (m97 structure): +bias +resid -> f32 out ----------------
__global__ __launch_bounds__(256) void gemm_bt2(const bf16* __restrict__ A,
                                                const bf16* __restrict__ W,
                                                const float* __restrict__ bias,
                                                const float* __restrict__ resid,
                                                float* __restrict__ outp, int N, int K) {
  __shared__ bf16 As[128 * 32];
  __shared__ bf16 Bs[128 * 32];
  const int t = threadIdx.x, lane = t & 63;
  const int w = t >> 6, wr = w >> 1, wc = w & 1;
  const int l15 = lane & 15, lg = lane >> 4;
  const int m0 = blockIdx.y * 128, n0 = blockIdx.x * 128;

  const int srow = t >> 2, scol = (t & 3) * 8;
  const bf16* gA0 = A + (size_t)(m0 + srow) * K + scol;
  const bf16* gA1 = A + (size_t)(m0 + 64 + srow) * K + scol;
  const bf16* gB0 = W + (size_t)(n0 + srow) * K + scol;
  const bf16* gB1 = W + (size_t)(n0 + 64 + srow) * K + scol;
  char* lA0 = (char*)As + t * 16;
  char* lA1 = (char*)As + 4096 + t * 16;
  char* lB0 = (char*)Bs + t * 16;
  char* lB1 = (char*)Bs + 4096 + t * 16;

  f32x4 acc[4][4];
#pragma unroll
  for (int i = 0; i < 4; i++)
#pragma unroll
    for (int j = 0; j < 4; j++) acc[i][j] = (f32x4){0.f, 0.f, 0.f, 0.f};

  const int tiles = K >> 5;
  for (int kt = 0; kt < tiles; ++kt) {
    __syncthreads();
    gll16(gA0, lA0); gll16(gA1, lA1);
    gll16(gB0, lB0); gll16(gB1, lB1);
    gA0 += 32; gA1 += 32; gB0 += 32; gB1 += 32;
    __syncthreads();
    bf16x8 af[4], bfv[4];
#pragma unroll
    for (int mi = 0; mi < 4; mi++)
      af[mi] = *(const bf16x8*)(As + (wr * 64 + mi * 16 + l15) * 32 + lg * 8);
#pragma unroll
    for (int ni = 0; ni < 4; ni++)
      bfv[ni] = *(const bf16x8*)(Bs + (wc * 64 + ni * 16 + l15) * 32 + lg * 8);
#pragma unroll
    for (int mi = 0; mi < 4; mi++)
#pragma unroll
      for (int ni = 0; ni < 4; ni++)
        acc[mi][ni] = MFMA_16x16x32(af[mi], bfv[ni], acc[mi][ni]);
  }

#pragma unroll
  for (int mi = 0; mi < 4; mi++) {
    const int row0 = m0 + wr * 64 + mi * 16 + lg * 4;
#pragma unroll
    for (int ni = 0; ni < 4; ni++) {
      const int col = n0 + wc * 64 + ni * 16 + l15;
      const float bc = bias[col];
#pragma unroll
      for (int r = 0; r < 4; r++) {
        const size_t idx = (size_t)(row0 + r) * N + col;
        outp[idx] = acc[mi][ni][r] + bc + resid[idx];
      }
    }
  }
}

// ---------------- V transpose (tiled, coalesced): vt[bh][d][s] ----------------
__global__ __launch_bounds__(256) void vtrans_kernel(const bf16* __restrict__ qkv,
                                                     bf16* __restrict__ vt) {
  __shared__ bf16 tile[64 * 80];
  const int bh = blockIdx.y, b = bh >> 4, h = bh & 15;
  const int s0 = blockIdx.x * 64;
  const int t = threadIdx.x;
#pragma unroll
  for (int c = t; c < 512; c += 256) {
    const int s = c >> 3, d0 = (c & 7) * 8;
    const bf16x8 v =
        *(const bf16x8*)(qkv + (size_t)(b * 2048 + s0 + s) * 3072 + 2048 + h * 64 + d0);
#pragma unroll
    for (int i = 0; i < 8; i++) {
      const int d = d0 + i;
      tile[d * 80 + (s ^ (8 * ((d >> 3) & 7)))] = v[i];
    }
  }
  __syncthreads();
#pragma unroll
  for (int c = t; c < 512; c += 256) {
    const int d = c >> 3, sc = (c & 7) * 8;
    const bf16x8 v = *(const bf16x8*)&tile[d * 80 + (sc ^ (8 * ((d >> 3) & 7)))];
    *(bf16x8*)(vt + ((size_t)bh * 64 + d) * 2048 + s0 + sc) = v;
  }
}

// ========== Flash attention (causal), swapped-QK in-register softmax ==========
// 4 waves x 32 q-rows = 128 q/block; 32x32x16 MFMA; S^T = mfma(K,Q) so each lane
// owns query l&31's scores; softmax fully in-register (1 shfl per reduce);
// P->bf16 via v_cvt_pk + half-exchange feeds PV directly. KV tiles 64, dbuf LDS.
__global__ __launch_bounds__(256) void attn_kernel(const bf16* __restrict__ qkv,
                                                   const bf16* __restrict__ vt,
                                                   bf16* __restrict__ attn_out) {
  __shared__ bf16 Ks[2][4096];
  __shared__ bf16 Vs[2][4096];
  const int t = threadIdx.x, lane = t & 63, w = t >> 6;
  const int l31 = lane & 31, lh = lane >> 5;
  const int bx = blockIdx.x, by = blockIdx.y;
  const int b = by >> 4, h = by & 15;
  const int g = (bx + by) & 15;
  const int qb = (by < 16) ? g : 15 - g;  // CU-pair trip counts sum to const
  const int qw = qb * 128 + w * 32;       // warp's first q (seq pos)
  const int qq = qw + l31;                // lane's q
  const int nt = 2 * qb + 2;

  const float cs = 0.18033688011112042f;  // 0.125 * log2(e)

  // Q fragments (B-operand: lane -> query col l&31, k-dims lh*8+0..7 per 16-chunk)
  bf16x8 qf[4];
  {
    const bf16* qp = qkv + (size_t)(b * 2048 + qq) * 3072 + h * 64 + lh * 8;
#pragma unroll
    for (int c = 0; c < 4; ++c) qf[c] = *(const bf16x8*)(qp + c * 16);
  }

  // staging (both-sides XOR swizzle, linear LDS dest)
  const int r0 = t >> 3, c16 = t & 7;
  const int swsl = 8 * (c16 ^ (r0 & 7));
  const bf16* kp0 = qkv + (size_t)(b * 2048 + r0) * 3072 + 1024 + h * 64 + swsl;
  const bf16* kp1 = qkv + (size_t)(b * 2048 + r0 + 32) * 3072 + 1024 + h * 64 + swsl;
  const bf16* vp0 = vt + ((size_t)by * 64 + r0) * 2048 + swsl;
  const bf16* vp1 = vp0 + (size_t)32 * 2048;

#define ASTAGE(buf)                          \
  do {                                       \
    gll16(kp0, &Ks[buf][t * 8]);             \
    gll16(kp1, &Ks[buf][2048 + t * 8]);      \
    gll16(vp0, &Vs[buf][t * 8]);             \
    gll16(vp1, &Vs[buf][2048 + t * 8]);      \
    kp0 += (size_t)64 * 3072;                \
    kp1 += (size_t)64 * 3072;                \
    vp0 += 64;                               \
    vp1 += 64;                               \
  } while (0)

  const f32x16 z16 = {0.f, 0.f, 0.f, 0.f, 0.f, 0.f, 0.f, 0.f,
                      0.f, 0.f, 0.f, 0.f, 0.f, 0.f, 0.f, 0.f};
  f32x16 oacc0 = z16, oacc1 = z16;
  float m = -1e30f, lsum = 0.f;

  ASTAGE(0);
  __syncthreads();
  int cur = 0;
  for (int tt = 0; tt < nt; ++tt) {
    const int kv0 = tt * 64;
    if (tt + 1 < nt) ASTAGE(cur ^ 1);
    if (kv0 <= qw + 31) {
      const bf16* kbp = Ks[cur];
      const bf16* vbp = Vs[cur];
      // QK^T (swapped): s[key][q], lane owns q = l31; keys (j&3)+8*(j>>2)+4*lh (+32 for s1)
      f32x16 s0v = z16, s1v = z16;
#pragma unroll
      for (int c = 0; c < 4; ++c) {
        const int slot = ((c * 2 + lh) ^ (l31 & 7)) * 16;
        const bf16x8 a0 = *(const bf16x8*)((const char*)kbp + l31 * 128 + slot);
        const bf16x8 a1 = *(const bf16x8*)((const char*)kbp + (32 + l31) * 128 + slot);
        s0v = MFMA32(a0, qf[c], s0v);
        s1v = MFMA32(a1, qf[c], s1v);
      }
      // causal mask: only the last active tile per warp needs it
      if (kv0 + 64 > qw) {
#pragma unroll
        for (int j = 0; j < 16; ++j) {
          const int kr = kv0 + (j & 3) + 8 * (j >> 2) + 4 * lh;
          if (kr > qq) s0v[j] = -1e30f;
          if (kr + 32 > qq) s1v[j] = -1e30f;
        }
      }
      // row max (own 32 + partner)
      float mx = -1e30f;
#pragma unroll
      for (int j = 0; j < 16; ++j) mx = fmaxf(mx, fmaxf(s0v[j], s1v[j]));
      mx = fmaxf(mx, __shfl_xor(mx, 32));
      const float mn = fmaxf(m, mx);
      const float alpha = exp2f((m - mn) * cs);
      m = mn;
      const float mcs = mn * cs;
      float rs = 0.f;
#pragma unroll
      for (int j = 0; j < 16; ++j) {
        s0v[j] = exp2f(__builtin_fmaf(s0v[j], cs, -mcs));
        s1v[j] = exp2f(__builtin_fmaf(s1v[j], cs, -mcs));
        rs += s0v[j] + s1v[j];
      }
      rs += __shfl_xor(rs, 32);
      lsum = lsum * alpha + rs;
#pragma unroll
      for (int j = 0; j < 16; ++j) { oacc0[j] *= alpha; oacc1[j] *= alpha; }
      // P -> bf16 words, exchange halves
      int w0[8], w1[8], x0[8], x1[8];
#pragma unroll
      for (int j = 0; j < 8; ++j) {
        w0[j] = cvtpk(s0v[2 * j], s0v[2 * j + 1]);
        w1[j] = cvtpk(s1v[2 * j], s1v[2 * j + 1]);
      }
#pragma unroll
      for (int j = 0; j < 8; ++j) {
        x0[j] = __shfl_xor(w0[j], 32);
        x1[j] = __shfl_xor(w1[j], 32);
      }
      // PV: O^T[d][q] += V^T-frag @ P^T-frag
#define PVHALF(WW, XX, KB)                                                        \
  do {                                                                            \
    _Pragma("unroll") for (int cc = 0; cc < 2; ++cc) {                            \
      union { int i[4]; bf16x8 v; } pf;                                           \
      pf.i[0] = lh ? XX[4 * cc + 2] : WW[4 * cc + 0];                             \
      pf.i[1] = lh ? XX[4 * cc + 3] : WW[4 * cc + 1];                             \
      pf.i[2] = lh ? WW[4 * cc + 2] : XX[4 * cc + 0];                             \
      pf.i[3] = lh ? WW[4 * cc + 3] : XX[4 * cc + 1];                             \
      const int slot = (((KB)*4 + cc * 2 + lh) ^ (l31 & 7)) * 16;                 \
      const bf16x8 v0 = *(const bf16x8*)((const char*)vbp + l31 * 128 + slot);    \
      const bf16x8 v1 = *(const bf16x8*)((const char*)vbp + (32 + l31) * 128 + slot); \
      oacc0 = MFMA32(v0, pf.v, oacc0);                                            \
      oacc1 = MFMA32(v1, pf.v, oacc1);                                            \
    }                                                                             \
  } while (0)
      PVHALF(w0, x0, 0);
      PVHALF(w1, x1, 1);
#undef PVHALF
    }
    __syncthreads();
    cur ^= 1;
  }
#undef ASTAGE

  const float rinv = 1.f / lsum;
  bf16* op = attn_out + (size_t)(b * 2048 + qq) * 1024 + h * 64;
#pragma unroll
  for (int gR = 0; gR < 4; ++gR) {
    bf16x4 o0, o1;
#pragma unroll
    for (int r = 0; r < 4; ++r) {
      o0[r] = (bf16)(oacc0[4 * gR + r] * rinv);
      o1[r] = (bf16)(oacc1[4 * gR + r] * rinv);
    }
    *(bf16x4*)(op + 8 * gR + 4 * lh) = o0;
    *(bf16x4*)(op + 32 + 8 * gR + 4 * lh) = o1;
  }
}

// ---------------- launch ----------------
extern "C" void kernel_launch(void* const* d_in, const int* in_sizes, int n_in,
                              void* d_out, int out_size, void* d_ws, size_t ws_size,
                              hipStream_t stream) {
  (void)in_sizes; (void)n_in; (void)out_size; (void)ws_size;
  const float* hidden = (const float*)d_in[0];
  const float* qkv_w  = (const float*)d_in[1];
  const float* qkv_b  = (const float*)d_in[2];
  const float* out_w  = (const float*)d_in[3];
  const float* out_b  = (const float*)d_in[4];
  const float* fc1_w  = (const float*)d_in[5];
  const float* fc1_b  = (const float*)d_in[6];
  const float* fc2_w  = (const float*)d_in[7];
  const float* fc2_b  = (const float*)d_in[8];
  const float* ln1_g  = (const float*)d_in[9];
  const float* ln1_b  = (const float*)d_in[10];
  const float* ln2_g  = (const float*)d_in[11];
  const float* ln2_b  = (const float*)d_in[12];
  float* outp = (float*)d_out;

  char* ws = (char*)d_ws;
  bf16*  ln1o = (bf16*)(ws);
  bf16*  qkvb = (bf16*)(ws + ((size_t)8 << 20));
  bf16*  vtb  = (bf16*)(ws + ((size_t)32 << 20));
  bf16*  atto = (bf16*)(ws + ((size_t)40 << 20));
  float* res1 = (float*)(ws + ((size_t)48 << 20));
  bf16*  ln2o = (bf16*)(ws + ((size_t)64 << 20));
  bf16*  ff1  = (bf16*)(ws + ((size_t)72 << 20));
  bf16*  wqkv = (bf16*)(ws + ((size_t)104 << 20));
  bf16*  wout = (bf16*)(ws + ((size_t)110 << 20));
  bf16*  wfc1 = (bf16*)(ws + ((size_t)112 << 20));
  bf16*  wfc2 = (bf16*)(ws + ((size_t)120 << 20));

  cast4_kernel<<<12288, 256, 0, stream>>>(qkv_w, wqkv, out_w, wout, fc1_w, wfc1, fc2_w, wfc2);

  ln_kernel<<<4096, 256, 0, stream>>>(hidden, ln1_g, ln1_b, ln1o);
  gemm256<0><<<192, 512, 0, stream>>>(ln1o, wqkv, qkv_b, qkvb, 3072, 1024, 12);
  vtrans_kernel<<<dim3(32, 32), 256, 0, stream>>>(qkvb, vtb);
  attn_kernel<<<dim3(16, 32), 256, 0, stream>>>(qkvb, vtb, atto);
  gemm_bt2<<<dim3(8, 32), 256, 0, stream>>>(atto, wout, out_b, hidden, res1, 1024, 1024);
  ln_kernel<<<4096, 256, 0, stream>>>(res1, ln2_g, ln2_b, ln2o);
  gemm256<1><<<256, 512, 0, stream>>>(ln2o, wfc1, fc1_b, ff1, 4096, 1024, 16);
  gemm_bt2<<<dim3(8, 32), 256, 0, stream>>>(ff1, wfc2, fc2_b, res1, outp, 1024, 4096);
}

// Round 5
// 261.584 us; speedup vs baseline: 1.9037x; 1.1856x over previous
//
#include <hip/hip_runtime.h>
#include <math.h>

using bf16   = __bf16;
using bf16x8 = __attribute__((ext_vector_type(8))) __bf16;
using bf16x4 = __attribute__((ext_vector_type(4))) __bf16;
using f32x4  = __attribute__((ext_vector_type(4))) float;
using f32x16 = __attribute__((ext_vector_type(16))) float;

#define MFMA_16x16x32(a, b, c) __builtin_amdgcn_mfma_f32_16x16x32_bf16((a), (b), (c), 0, 0, 0)
#define MFMA32(a, b, c) __builtin_amdgcn_mfma_f32_32x32x16_bf16((a), (b), (c), 0, 0, 0)

__device__ __forceinline__ void gll16(const void* g, void* l) {
  __builtin_amdgcn_global_load_lds((const __attribute__((address_space(1))) void*)g,
                                   (__attribute__((address_space(3))) void*)l,
                                   16, 0, 0);
}

__device__ __forceinline__ int cvtpk(float lo, float hi) {
  int r;
  asm("v_cvt_pk_bf16_f32 %0, %1, %2" : "=v"(r) : "v"(lo), "v"(hi));
  return r;
}

// ---------------- fused fp32 -> bf16 weight casts ----------------
__global__ __launch_bounds__(256) void cast4_kernel(const float* __restrict__ s0, bf16* d0,
                                                    const float* __restrict__ s1, bf16* d1,
                                                    const float* __restrict__ s2, bf16* d2,
                                                    const float* __restrict__ s3, bf16* d3) {
  int i = blockIdx.x * 256 + threadIdx.x;  // in float4 units
  const float* s;
  bf16* d;
  if (i < 786432) { s = s0; d = d0; }
  else if (i < 1048576) { s = s1; d = d1; i -= 786432; }
  else if (i < 2097152) { s = s2; d = d2; i -= 1048576; }
  else { s = s3; d = d3; i -= 2097152; }
  float4 v = ((const float4*)s)[i];
  bf16x4 o;
  o[0] = (bf16)v.x; o[1] = (bf16)v.y; o[2] = (bf16)v.z; o[3] = (bf16)v.w;
  ((bf16x4*)d)[i] = o;
}

// ---------------- LayerNorm (D=1024), fp32 in -> bf16 out ----------------
__global__ __launch_bounds__(256) void ln_kernel(const float* __restrict__ x,
                                                 const float* __restrict__ g,
                                                 const float* __restrict__ b,
                                                 bf16* __restrict__ out) {
  const int row = blockIdx.x, t = threadIdx.x;
  const float4 v = ((const float4*)(x + (size_t)row * 1024))[t];
  float s1 = v.x + v.y + v.z + v.w;
  float s2 = v.x * v.x + v.y * v.y + v.z * v.z + v.w * v.w;
#pragma unroll
  for (int d = 32; d; d >>= 1) {
    s1 += __shfl_xor(s1, d);
    s2 += __shfl_xor(s2, d);
  }
  __shared__ float red[8];
  const int w = t >> 6;
  if ((t & 63) == 0) { red[w] = s1; red[4 + w] = s2; }
  __syncthreads();
  s1 = red[0] + red[1] + red[2] + red[3];
  s2 = red[4] + red[5] + red[6] + red[7];
  const float mu = s1 * (1.f / 1024.f);
  const float rstd = rsqrtf(s2 * (1.f / 1024.f) - mu * mu + 1e-5f);
  const float4 gv = ((const float4*)g)[t];
  const float4 bv = ((const float4*)b)[t];
  bf16x4 o;
  o[0] = (bf16)((v.x - mu) * rstd * gv.x + bv.x);
  o[1] = (bf16)((v.y - mu) * rstd * gv.y + bv.y);
  o[2] = (bf16)((v.z - mu) * rstd * gv.z + bv.z);
  o[3] = (bf16)((v.w - mu) * rstd * gv.w + bv.w);
  ((bf16x4*)(out + (size_t)row * 1024))[t] = o;
}

// ============ 256x256 8-phase GEMM: C = A[M,K] @ W[N,K]^T ============
template <int EPI>
__global__ __launch_bounds__(512, 2) void gemm256(const bf16* __restrict__ A,
                                                  const bf16* __restrict__ W,
                                                  const float* __restrict__ bias,
                                                  bf16* __restrict__ outp, int N, int K,
                                                  int nbx) {
  __shared__ __align__(1024) bf16 lds[65536];
  const int t = threadIdx.x, lane = t & 63, w = t >> 6;
  const int wm = w >> 2, wn = w & 3;
  const int l15 = lane & 15, lg = lane >> 4;

  const int nwg = gridDim.x, cpx = nwg >> 3, bid = blockIdx.x;
  const int swz = (bid & 7) * cpx + (bid >> 3);
  const int bx = swz % nbx, by = swz / nbx;
  const int m0 = by * 256, n0 = bx * 256;

  const bf16* src[8];
  int dst[8];
  {
    const int ss[2] = {t, t + 512};
#pragma unroll
    for (int i = 0; i < 2; i++) {
      const int d = ss[i] * 16;
      const int L = d ^ (((d >> 9) & 1) << 5);
      const int r = L >> 7, coff = (L & 127) >> 1;
#pragma unroll
      for (int hf = 0; hf < 2; hf++) {
        src[hf * 2 + i]     = A + (size_t)(m0 + hf * 128 + r) * K + coff;
        src[4 + hf * 2 + i] = W + (size_t)(n0 + hf * 128 + r) * K + coff;
        dst[hf * 2 + i]     = hf * 8192 + ss[i] * 8;
        dst[4 + hf * 2 + i] = 16384 + hf * 8192 + ss[i] * 8;
      }
    }
  }

#define STAGE256(db_)                                   \
  do {                                                  \
    _Pragma("unroll") for (int u = 0; u < 8; u++) {     \
      gll16(src[u], lds + (db_)*32768 + dst[u]);        \
      src[u] += 64;                                     \
    }                                                   \
  } while (0)

  f32x4 acc[8][4];
#pragma unroll
  for (int mi = 0; mi < 8; mi++)
#pragma unroll
    for (int ni = 0; ni < 4; ni++) acc[mi][ni] = (f32x4){0.f, 0.f, 0.f, 0.f};

  const int ntiles = K >> 6;
  STAGE256(0);
  asm volatile("s_waitcnt vmcnt(0)" ::: "memory");
  __builtin_amdgcn_s_barrier();

  for (int kt = 0; kt < ntiles; ++kt) {
    const int db = kt & 1;
    const bf16* Ab = lds + db * 32768 + wm * 8192;
    const bf16* Bb = lds + db * 32768 + 16384 + (wn >> 1) * 8192;
    bf16x8 bfr[4][2];
#pragma unroll
    for (int p = 0; p < 4; ++p) {
      bf16x8 af[2][2];
#pragma unroll
      for (int mi2 = 0; mi2 < 2; ++mi2)
#pragma unroll
        for (int ks = 0; ks < 2; ++ks) {
          const int row = (2 * p + mi2) * 16 + l15;
          const int Pb = (row * 128 + ks * 64 + lg * 16) ^ (((row >> 2) & 1) << 5);
          af[mi2][ks] = *(const bf16x8*)((const char*)Ab + Pb);
        }
      if (p == 0) {
#pragma unroll
        for (int ni = 0; ni < 4; ++ni)
#pragma unroll
          for (int ks = 0; ks < 2; ++ks) {
            const int row = (wn & 1) * 64 + ni * 16 + l15;
            const int Pb = (row * 128 + ks * 64 + lg * 16) ^ (((row >> 2) & 1) << 5);
            bfr[ni][ks] = *(const bf16x8*)((const char*)Bb + Pb);
          }
        if (kt + 1 < ntiles) STAGE256(db ^ 1);
      }
      __builtin_amdgcn_s_barrier();
      asm volatile("s_waitcnt lgkmcnt(0)" ::: "memory");
      __builtin_amdgcn_sched_barrier(0);
      __builtin_amdgcn_s_setprio(1);
#pragma unroll
      for (int ks = 0; ks < 2; ++ks)
#pragma unroll
        for (int ni = 0; ni < 4; ++ni) {
          acc[2 * p][ni] = MFMA_16x16x32(af[0][ks], bfr[ni][ks], acc[2 * p][ni]);
          acc[2 * p + 1][ni] = MFMA_16x16x32(af[1][ks], bfr[ni][ks], acc[2 * p + 1][ni]);
        }
      __builtin_amdgcn_s_setprio(0);
      if (p == 3) asm volatile("s_waitcnt vmcnt(0)" ::: "memory");
      __builtin_amdgcn_s_barrier();
    }
  }
#undef STAGE256

#pragma unroll
  for (int mi = 0; mi < 8; ++mi) {
    const int row0 = m0 + wm * 128 + mi * 16 + lg * 4;
#pragma unroll
    for (int ni = 0; ni < 4; ++ni) {
      const int col = n0 + wn * 64 + ni * 16 + l15;
      const float bc = bias[col];
#pragma unroll
      for (int r = 0; r < 4; ++r) {
        float v = acc[mi][ni][r] + bc;
        if (EPI == 1) v = 0.5f * v * (1.f + erff(v * 0.70710678118f));
        outp[(size_t)(row0 + r) * N + col] = (bf16)v;
      }
    }
  }
}

// ============ 128x128 8-phase GEMM (BK=128): +bias +resid -> f32 out ============
// Same schedule as gemm256 at 128^2 geometry: 512 thr (2Mx4N waves, 64x32/wave),
// 128KB LDS dbuf, 256B rows swizzled slot^=(row&7), counted vmcnt, setprio.
__global__ __launch_bounds__(512, 2) void gemm128(const bf16* __restrict__ A,
                                                  const bf16* __restrict__ W,
                                                  const float* __restrict__ bias,
                                                  const float* __restrict__ resid,
                                                  float* __restrict__ outp, int N, int K,
                                                  int nbx) {
  __shared__ __align__(1024) bf16 lds[65536];  // [db][A 32KB | B 32KB]
  const int t = threadIdx.x, lane = t & 63, w = t >> 6;
  const int wm = w >> 2, wn = w & 3;
  const int l15 = lane & 15, lg = lane >> 4;

  const int nwg = gridDim.x, cpx = nwg >> 3, bid = blockIdx.x;
  const int swz = (bid & 7) * cpx + (bid >> 3);
  const int bx = swz % nbx, by = swz / nbx;
  const int m0 = by * 128, n0 = bx * 128;

  // staging: 8 units = {A,B} x 4 issues; off = i*8192 + t*16 bytes in region
  const bf16* src[8];
  int dst[8];
#pragma unroll
  for (int i = 0; i < 4; i++) {
    const int off = i * 8192 + t * 16;
    const int row = off >> 8, slot = (off >> 4) & 15;
    const int col = (slot ^ (row & 7)) * 8;  // pre-swizzled source col (elems)
    src[i]     = A + (size_t)(m0 + row) * K + col;
    src[4 + i] = W + (size_t)(n0 + row) * K + col;
    dst[i]     = off >> 1;             // LDS elem offset (linear dest)
    dst[4 + i] = 16384 + (off >> 1);
  }

#define STAGE128(db_)                                   \
  do {                                                  \
    _Pragma("unroll") for (int u = 0; u < 8; u++) {     \
      gll16(src[u], lds + (db_)*32768 + dst[u]);        \
      src[u] += 128;                                    \
    }                                                   \
  } while (0)

  f32x4 acc[4][2];
#pragma unroll
  for (int mi = 0; mi < 4; mi++)
#pragma unroll
    for (int ni = 0; ni < 2; ni++) acc[mi][ni] = (f32x4){0.f, 0.f, 0.f, 0.f};

  const int ntiles = K >> 7;
  STAGE128(0);
  asm volatile("s_waitcnt vmcnt(0)" ::: "memory");
  __builtin_amdgcn_s_barrier();

  for (int kt = 0; kt < ntiles; ++kt) {
    const int db = kt & 1;
    const char* Ab = (const char*)(lds + db * 32768);
    const char* Bb = (const char*)(lds + db * 32768 + 16384);
#pragma unroll
    for (int p = 0; p < 4; ++p) {  // p = 32-wide K-slice
      bf16x8 af[4], bfr[2];
#pragma unroll
      for (int mi = 0; mi < 4; ++mi) {
        const int row = wm * 64 + mi * 16 + l15;
        af[mi] = *(const bf16x8*)(Ab + row * 256 + (((p * 4 + lg) ^ (row & 7)) << 4));
      }
#pragma unroll
      for (int ni = 0; ni < 2; ++ni) {
        const int row = wn * 32 + ni * 16 + l15;
        bfr[ni] = *(const bf16x8*)(Bb + row * 256 + (((p * 4 + lg) ^ (row & 7)) << 4));
      }
      if (p == 0 && kt + 1 < ntiles) STAGE128(db ^ 1);
      __builtin_amdgcn_s_barrier();
      asm volatile("s_waitcnt lgkmcnt(0)" ::: "memory");
      __builtin_amdgcn_sched_barrier(0);
      __builtin_amdgcn_s_setprio(1);
#pragma unroll
      for (int mi = 0; mi < 4; ++mi)
#pragma unroll
        for (int ni = 0; ni < 2; ++ni)
          acc[mi][ni] = MFMA_16x16x32(af[mi], bfr[ni], acc[mi][ni]);
      __builtin_amdgcn_s_setprio(0);
      if (p == 3) asm volatile("s_waitcnt vmcnt(0)" ::: "memory");
      __builtin_amdgcn_s_barrier();
    }
  }
#undef STAGE128

#pragma unroll
  for (int mi = 0; mi < 4; ++mi) {
    const int row0 = m0 + wm * 64 + mi * 16 + lg * 4;
#pragma unroll
    for (int ni = 0; ni < 2; ++ni) {
      const int col = n0 + wn * 32 + ni * 16 + l15;
      const float bc = bias[col];
#pragma unroll
      for (int r = 0; r < 4; ++r) {
        const size_t idx = (size_t)(row0 + r) * N + col;
        outp[idx] = acc[mi][ni][r] + bc + resid[idx];
      }
    }
  }
}

// ---------------- V transpose (tiled, coalesced): vt[bh][d][s] ----------------
__global__ __launch_bounds__(256) void vtrans_kernel(const bf16* __restrict__ qkv,
                                                     bf16* __restrict__ vt) {
  __shared__ bf16 tile[64 * 80];
  const int bh = blockIdx.y, b = bh >> 4, h = bh & 15;
  const int s0 = blockIdx.x * 64;
  const int t = threadIdx.x;
#pragma unroll
  for (int c = t; c < 512; c += 256) {
    const int s = c >> 3, d0 = (c & 7) * 8;
    const bf16x8 v =
        *(const bf16x8*)(qkv + (size_t)(b * 2048 + s0 + s) * 3072 + 2048 + h * 64 + d0);
#pragma unroll
    for (int i = 0; i < 8; i++) {
      const int d = d0 + i;
      tile[d * 80 + (s ^ (8 * ((d >> 3) & 7)))] = v[i];
    }
  }
  __syncthreads();
#pragma unroll
  for (int c = t; c < 512; c += 256) {
    const int d = c >> 3, sc = (c & 7) * 8;
    const bf16x8 v = *(const bf16x8*)&tile[d * 80 + (sc ^ (8 * ((d >> 3) & 7)))];
    *(bf16x8*)(vt + ((size_t)bh * 64 + d) * 2048 + s0 + sc) = v;
  }
}

// ========== Flash attention (causal), swapped-QK in-register softmax ==========
__global__ __launch_bounds__(256) void attn_kernel(const bf16* __restrict__ qkv,
                                                   const bf16* __restrict__ vt,
                                                   bf16* __restrict__ attn_out) {
  __shared__ bf16 Ks[2][4096];
  __shared__ bf16 Vs[2][4096];
  const int t = threadIdx.x, lane = t & 63, w = t >> 6;
  const int l31 = lane & 31, lh = lane >> 5;
  const int bx = blockIdx.x, by = blockIdx.y;
  const int b = by >> 4, h = by & 15;
  const int g = (bx + by) & 15;
  const int qb = (by < 16) ? g : 15 - g;
  const int qw = qb * 128 + w * 32;
  const int qq = qw + l31;
  const int nt = 2 * qb + 2;

  const float cs = 0.18033688011112042f;  // 0.125 * log2(e)

  bf16x8 qf[4];
  {
    const bf16* qp = qkv + (size_t)(b * 2048 + qq) * 3072 + h * 64 + lh * 8;
#pragma unroll
    for (int c = 0; c < 4; ++c) qf[c] = *(const bf16x8*)(qp + c * 16);
  }

  const int r0 = t >> 3, c16 = t & 7;
  const int swsl = 8 * (c16 ^ (r0 & 7));
  const bf16* kp0 = qkv + (size_t)(b * 2048 + r0) * 3072 + 1024 + h * 64 + swsl;
  const bf16* kp1 = qkv + (size_t)(b * 2048 + r0 + 32) * 3072 + 1024 + h * 64 + swsl;
  const bf16* vp0 = vt + ((size_t)by * 64 + r0) * 2048 + swsl;
  const bf16* vp1 = vp0 + (size_t)32 * 2048;

#define ASTAGE(buf)                          \
  do {                                       \
    gll16(kp0, &Ks[buf][t * 8]);             \
    gll16(kp1, &Ks[buf][2048 + t * 8]);      \
    gll16(vp0, &Vs[buf][t * 8]);             \
    gll16(vp1, &Vs[buf][2048 + t * 8]);      \
    kp0 += (size_t)64 * 3072;                \
    kp1 += (size_t)64 * 3072;                \
    vp0 += 64;                               \
    vp1 += 64;                               \
  } while (0)

  const f32x16 z16 = {0.f, 0.f, 0.f, 0.f, 0.f, 0.f, 0.f, 0.f,
                      0.f, 0.f, 0.f, 0.f, 0.f, 0.f, 0.f, 0.f};
  f32x16 oacc0 = z16, oacc1 = z16;
  float m = -1e30f, lsum = 0.f;

  ASTAGE(0);
  __syncthreads();
  int cur = 0;
  for (int tt = 0; tt < nt; ++tt) {
    const int kv0 = tt * 64;
    if (tt + 1 < nt) ASTAGE(cur ^ 1);
    if (kv0 <= qw + 31) {
      const bf16* kbp = Ks[cur];
      const bf16* vbp = Vs[cur];
      f32x16 s0v = z16, s1v = z16;
#pragma unroll
      for (int c = 0; c < 4; ++c) {
        const int slot = ((c * 2 + lh) ^ (l31 & 7)) * 16;
        const bf16x8 a0 = *(const bf16x8*)((const char*)kbp + l31 * 128 + slot);
        const bf16x8 a1 = *(const bf16x8*)((const char*)kbp + (32 + l31) * 128 + slot);
        s0v = MFMA32(a0, qf[c], s0v);
        s1v = MFMA32(a1, qf[c], s1v);
      }
      if (kv0 + 64 > qw) {
#pragma unroll
        for (int j = 0; j < 16; ++j) {
          const int kr = kv0 + (j & 3) + 8 * (j >> 2) + 4 * lh;
          if (kr > qq) s0v[j] = -1e30f;
          if (kr + 32 > qq) s1v[j] = -1e30f;
        }
      }
      float mx = -1e30f;
#pragma unroll
      for (int j = 0; j < 16; ++j) mx = fmaxf(mx, fmaxf(s0v[j], s1v[j]));
      mx = fmaxf(mx, __shfl_xor(mx, 32));
      const float mn = fmaxf(m, mx);
      const float alpha = exp2f((m - mn) * cs);
      m = mn;
      const float mcs = mn * cs;
      float rs = 0.f;
#pragma unroll
      for (int j = 0; j < 16; ++j) {
        s0v[j] = exp2f(__builtin_fmaf(s0v[j], cs, -mcs));
        s1v[j] = exp2f(__builtin_fmaf(s1v[j], cs, -mcs));
        rs += s0v[j] + s1v[j];
      }
      rs += __shfl_xor(rs, 32);
      lsum = lsum * alpha + rs;
#pragma unroll
      for (int j = 0; j < 16; ++j) { oacc0[j] *= alpha; oacc1[j] *= alpha; }
      int w0[8], w1[8], x0[8], x1[8];
#pragma unroll
      for (int j = 0; j < 8; ++j) {
        w0[j] = cvtpk(s0v[2 * j], s0v[2 * j + 1]);
        w1[j] = cvtpk(s1v[2 * j], s1v[2 * j + 1]);
      }
#pragma unroll
      for (int j = 0; j < 8; ++j) {
        x0[j] = __shfl_xor(w0[j], 32);
        x1[j] = __shfl_xor(w1[j], 32);
      }
#define PVHALF(WW, XX, KB)                                                        \
  do {                                                                            \
    _Pragma("unroll") for (int cc = 0; cc < 2; ++cc) {                            \
      union { int i[4]; bf16x8 v; } pf;                                           \
      pf.i[0] = lh ? XX[4 * cc + 2] : WW[4 * cc + 0];                             \
      pf.i[1] = lh ? XX[4 * cc + 3] : WW[4 * cc + 1];                             \
      pf.i[2] = lh ? WW[4 * cc + 2] : XX[4 * cc + 0];                             \
      pf.i[3] = lh ? WW[4 * cc + 3] : XX[4 * cc + 1];                             \
      const int slot = (((KB)*4 + cc * 2 + lh) ^ (l31 & 7)) * 16;                 \
      const bf16x8 v0 = *(const bf16x8*)((const char*)vbp + l31 * 128 + slot);    \
      const bf16x8 v1 = *(const bf16x8*)((const char*)vbp + (32 + l31) * 128 + slot); \
      oacc0 = MFMA32(v0, pf.v, oacc0);                                            \
      oacc1 = MFMA32(v1, pf.v, oacc1);                                            \
    }                                                                             \
  } while (0)
      PVHALF(w0, x0, 0);
      PVHALF(w1, x1, 1);
#undef PVHALF
    }
    __syncthreads();
    cur ^= 1;
  }
#undef ASTAGE

  const float rinv = 1.f / lsum;
  bf16* op = attn_out + (size_t)(b * 2048 + qq) * 1024 + h * 64;
#pragma unroll
  for (int gR = 0; gR < 4; ++gR) {
    bf16x4 o0, o1;
#pragma unroll
    for (int r = 0; r < 4; ++r) {
      o0[r] = (bf16)(oacc0[4 * gR + r] * rinv);
      o1[r] = (bf16)(oacc1[4 * gR + r] * rinv);
    }
    *(bf16x4*)(op + 8 * gR + 4 * lh) = o0;
    *(bf16x4*)(op + 32 + 8 * gR + 4 * lh) = o1;
  }
}

// ---------------- launch ----------------
extern "C" void kernel_launch(void* const* d_in, const int* in_sizes, int n_in,
                              void* d_out, int out_size, void* d_ws, size_t ws_size,
                              hipStream_t stream) {
  (void)in_sizes; (void)n_in; (void)out_size; (void)ws_size;
  const float* hidden = (const float*)d_in[0];
  const float* qkv_w  = (const float*)d_in[1];
  const float* qkv_b  = (const float*)d_in[2];
  const float* out_w  = (const float*)d_in[3];
  const float* out_b  = (const float*)d_in[4];
  const float* fc1_w  = (const float*)d_in[5];
  const float* fc1_b  = (const float*)d_in[6];
  const float* fc2_w  = (const float*)d_in[7];
  const float* fc2_b  = (const float*)d_in[8];
  const float* ln1_g  = (const float*)d_in[9];
  const float* ln1_b  = (const float*)d_in[10];
  const float* ln2_g  = (const float*)d_in[11];
  const float* ln2_b  = (const float*)d_in[12];
  float* outp = (float*)d_out;

  char* ws = (char*)d_ws;
  bf16*  ln1o = (bf16*)(ws);
  bf16*  qkvb = (bf16*)(ws + ((size_t)8 << 20));
  bf16*  vtb  = (bf16*)(ws + ((size_t)32 << 20));
  bf16*  atto = (bf16*)(ws + ((size_t)40 << 20));
  float* res1 = (float*)(ws + ((size_t)48 << 20));
  bf16*  ln2o = (bf16*)(ws + ((size_t)64 << 20));
  bf16*  ff1  = (bf16*)(ws + ((size_t)72 << 20));
  bf16*  wqkv = (bf16*)(ws + ((size_t)104 << 20));
  bf16*  wout = (bf16*)(ws + ((size_t)110 << 20));
  bf16*  wfc1 = (bf16*)(ws + ((size_t)112 << 20));
  bf16*  wfc2 = (bf16*)(ws + ((size_t)120 << 20));

  cast4_kernel<<<12288, 256, 0, stream>>>(qkv_w, wqkv, out_w, wout, fc1_w, wfc1, fc2_w, wfc2);

  ln_kernel<<<4096, 256, 0, stream>>>(hidden, ln1_g, ln1_b, ln1o);
  gemm256<0><<<192, 512, 0, stream>>>(ln1o, wqkv, qkv_b, qkvb, 3072, 1024, 12);
  vtrans_kernel<<<dim3(32, 32), 256, 0, stream>>>(qkvb, vtb);
  attn_kernel<<<dim3(16, 32), 256, 0, stream>>>(qkvb, vtb, atto);
  // out projection + residual -> res1 (f32): 128^2 8-phase, grid 8x32=256
  gemm128<<<256, 512, 0, stream>>>(atto, wout, out_b, hidden, res1, 1024, 1024, 8);
  ln_kernel<<<4096, 256, 0, stream>>>(res1, ln2_g, ln2_b, ln2o);
  gemm256<1><<<256, 512, 0, stream>>>(ln2o, wfc1, fc1_b, ff1, 4096, 1024, 16);
  // FC2 + residual -> d_out: grid 8x32=256, K=4096
  gemm128<<<256, 512, 0, stream>>>(ff1, wfc2, fc2_b, res1, outp, 1024, 4096, 8);
}